// Round 1
// baseline (1378.615 us; speedup 1.0000x reference)
//
#include <hip/hip_runtime.h>
#include <hip/hip_bf16.h>

#define N_NODES 100000
#define N_EDGES 1600000
#define DIM 128

// ---------------- Kernel 1: Wsum = W0 + W1 + W2 ----------------
__global__ void wsum_kernel(const float* __restrict__ W0, const float* __restrict__ W1,
                            const float* __restrict__ W2, float* __restrict__ Wsum) {
    int i = blockIdx.x * blockDim.x + threadIdx.x;
    if (i < DIM * DIM) Wsum[i] = W0[i] + W1[i] + W2[i];
}

// ---------------- Kernel 2: H = x @ Wsum + one_hot_h ----------------
// Block: 256 threads, handles 32 rows x 128 cols.
// Thread (j = tid&31, rg = tid>>5): computes rows rg*4..rg*4+3, cols 4j..4j+3.
#define GEMM_ROWS 32
__global__ __launch_bounds__(256) void gemm_kernel(const float* __restrict__ x,
                                                   const float* __restrict__ oh,
                                                   const float* __restrict__ Wsum,
                                                   float* __restrict__ H) {
    __shared__ float ws[DIM * DIM];        // 64 KB
    __shared__ float xs[GEMM_ROWS * DIM];  // 16 KB
    int tid = threadIdx.x;

    // cooperative load of Wsum (4096 float4 / 256 threads = 16 each)
    for (int i = tid; i < DIM * DIM / 4; i += 256)
        ((float4*)ws)[i] = ((const float4*)Wsum)[i];

    long long row0 = (long long)blockIdx.x * GEMM_ROWS;
    // x tile: 32*128/4 = 1024 float4 / 256 = 4 each
    for (int i = tid; i < GEMM_ROWS * DIM / 4; i += 256)
        ((float4*)xs)[i] = ((const float4*)(x + row0 * DIM))[i];

    __syncthreads();

    int j  = (tid & 31) * 4;  // 4 consecutive cols
    int r0 = (tid >> 5) * 4;  // 4 rows

    float acc[4][4];
#pragma unroll
    for (int r = 0; r < 4; ++r) {
        float4 o = *(const float4*)&oh[(row0 + r0 + r) * DIM + j];
        acc[r][0] = o.x; acc[r][1] = o.y; acc[r][2] = o.z; acc[r][3] = o.w;
    }

    for (int k = 0; k < DIM; k += 4) {
        float4 wv[4];
#pragma unroll
        for (int kk = 0; kk < 4; ++kk)
            wv[kk] = *(const float4*)&ws[(k + kk) * DIM + j];
#pragma unroll
        for (int r = 0; r < 4; ++r) {
            float4 xv = *(const float4*)&xs[(r0 + r) * DIM + k];
            float xk0 = xv.x, xk1 = xv.y, xk2 = xv.z, xk3 = xv.w;
            acc[r][0] += xk0 * wv[0].x; acc[r][1] += xk0 * wv[0].y;
            acc[r][2] += xk0 * wv[0].z; acc[r][3] += xk0 * wv[0].w;
            acc[r][0] += xk1 * wv[1].x; acc[r][1] += xk1 * wv[1].y;
            acc[r][2] += xk1 * wv[1].z; acc[r][3] += xk1 * wv[1].w;
            acc[r][0] += xk2 * wv[2].x; acc[r][1] += xk2 * wv[2].y;
            acc[r][2] += xk2 * wv[2].z; acc[r][3] += xk2 * wv[2].w;
            acc[r][0] += xk3 * wv[3].x; acc[r][1] += xk3 * wv[3].y;
            acc[r][2] += xk3 * wv[3].z; acc[r][3] += xk3 * wv[3].w;
        }
    }

#pragma unroll
    for (int r = 0; r < 4; ++r) {
        float4 o = {acc[r][0], acc[r][1], acc[r][2], acc[r][3]};
        *(float4*)&H[(row0 + r0 + r) * DIM + j] = o;
    }
}

// ---------------- Kernel 3: scatter-add ----------------
// One wave (64 lanes) per edge: lane handles cols 2*lane, 2*lane+1.
// Edge metadata loads are wave-uniform -> broadcast. H gather: 512B/wave contiguous.
__global__ __launch_bounds__(256) void scatter_kernel(const float* __restrict__ H,
                                                      const int* __restrict__ rows,
                                                      const int* __restrict__ cols,
                                                      const float* __restrict__ vals,
                                                      float* __restrict__ out) {
    long long total = (long long)N_EDGES * 64;
    long long stride = (long long)gridDim.x * blockDim.x;
    for (long long idx = (long long)blockIdx.x * blockDim.x + threadIdx.x;
         idx < total; idx += stride) {
        int e = (int)(idx >> 6);
        int j = ((int)idx & 63) * 2;
        int r = rows[e];
        int c = cols[e];
        float v = vals[e];
        float2 h = *(const float2*)&H[(long long)c * DIM + j];
        float* op = &out[(long long)r * DIM + j];
        atomicAdd(op,     v * h.x);
        atomicAdd(op + 1, v * h.y);
    }
}

extern "C" void kernel_launch(void* const* d_in, const int* in_sizes, int n_in,
                              void* d_out, int out_size, void* d_ws, size_t ws_size,
                              hipStream_t stream) {
    const float* x    = (const float*)d_in[0];
    const float* oh   = (const float*)d_in[1];
    const float* W0   = (const float*)d_in[2];
    const float* W1   = (const float*)d_in[3];
    const float* W2   = (const float*)d_in[4];
    const int*   rows = (const int*)d_in[5];
    const int*   cols = (const int*)d_in[6];
    const float* vals = (const float*)d_in[7];
    float* out = (float*)d_out;

    // workspace layout: Wsum (64KB) | H (N_NODES*128 floats = 51.2MB)
    float* Wsum = (float*)d_ws;
    float* H    = (float*)((char*)d_ws + 64 * 1024);

    // 1. Wsum
    wsum_kernel<<<(DIM * DIM + 255) / 256, 256, 0, stream>>>(W0, W1, W2, Wsum);

    // 2. H = x @ Wsum + one_hot_h   (100000 rows / 32 per block = 3125 blocks)
    gemm_kernel<<<N_NODES / GEMM_ROWS, 256, 0, stream>>>(x, oh, Wsum, H);

    // 3. zero output
    hipMemsetAsync(d_out, 0, (size_t)out_size * sizeof(float), stream);

    // 4. scatter
    scatter_kernel<<<8192, 256, 0, stream>>>(H, rows, cols, vals, out);
}

// Round 2
// 385.817 us; speedup vs baseline: 3.5732x; 3.5732x over previous
//
#include <hip/hip_runtime.h>
#include <hip/hip_bf16.h>

#define N_NODES 100000
#define N_EDGES 1600000
#define DIM 128
#define NCH 98  // ceil(N_NODES / 1024)

// ---------------- Kernel 1: Wsum = W0 + W1 + W2 ----------------
__global__ void wsum_kernel(const float* __restrict__ W0, const float* __restrict__ W1,
                            const float* __restrict__ W2, float* __restrict__ Wsum) {
    int i = blockIdx.x * blockDim.x + threadIdx.x;
    if (i < DIM * DIM) Wsum[i] = W0[i] + W1[i] + W2[i];
}

// ---------------- Kernel 2: H = x @ Wsum + one_hot_h ----------------
#define GEMM_ROWS 32
__global__ __launch_bounds__(256) void gemm_kernel(const float* __restrict__ x,
                                                   const float* __restrict__ oh,
                                                   const float* __restrict__ Wsum,
                                                   float* __restrict__ H) {
    __shared__ float ws[DIM * DIM];        // 64 KB
    __shared__ float xs[GEMM_ROWS * DIM];  // 16 KB
    int tid = threadIdx.x;

    for (int i = tid; i < DIM * DIM / 4; i += 256)
        ((float4*)ws)[i] = ((const float4*)Wsum)[i];

    long long row0 = (long long)blockIdx.x * GEMM_ROWS;
    for (int i = tid; i < GEMM_ROWS * DIM / 4; i += 256)
        ((float4*)xs)[i] = ((const float4*)(x + row0 * DIM))[i];

    __syncthreads();

    int j  = (tid & 31) * 4;
    int r0 = (tid >> 5) * 4;

    float acc[4][4];
#pragma unroll
    for (int r = 0; r < 4; ++r) {
        float4 o = *(const float4*)&oh[(row0 + r0 + r) * DIM + j];
        acc[r][0] = o.x; acc[r][1] = o.y; acc[r][2] = o.z; acc[r][3] = o.w;
    }

    for (int k = 0; k < DIM; k += 4) {
        float4 wv[4];
#pragma unroll
        for (int kk = 0; kk < 4; ++kk)
            wv[kk] = *(const float4*)&ws[(k + kk) * DIM + j];
#pragma unroll
        for (int r = 0; r < 4; ++r) {
            float4 xv = *(const float4*)&xs[(r0 + r) * DIM + k];
            acc[r][0] += xv.x * wv[0].x; acc[r][1] += xv.x * wv[0].y;
            acc[r][2] += xv.x * wv[0].z; acc[r][3] += xv.x * wv[0].w;
            acc[r][0] += xv.y * wv[1].x; acc[r][1] += xv.y * wv[1].y;
            acc[r][2] += xv.y * wv[1].z; acc[r][3] += xv.y * wv[1].w;
            acc[r][0] += xv.z * wv[2].x; acc[r][1] += xv.z * wv[2].y;
            acc[r][2] += xv.z * wv[2].z; acc[r][3] += xv.z * wv[2].w;
            acc[r][0] += xv.w * wv[3].x; acc[r][1] += xv.w * wv[3].y;
            acc[r][2] += xv.w * wv[3].z; acc[r][3] += xv.w * wv[3].w;
        }
    }

#pragma unroll
    for (int r = 0; r < 4; ++r) {
        float4 o = {acc[r][0], acc[r][1], acc[r][2], acc[r][3]};
        *(float4*)&H[(row0 + r0 + r) * DIM + j] = o;
    }
}

// ---------------- CSR build ----------------
__global__ void hist_kernel(const int* __restrict__ rows, int* __restrict__ cnt) {
    int stride = gridDim.x * blockDim.x;
    for (int e = blockIdx.x * blockDim.x + threadIdx.x; e < N_EDGES; e += stride)
        atomicAdd(&cnt[rows[e]], 1);
}

// Per-chunk exclusive scan: block b handles counts [b*1024, b*1024+1024).
__global__ __launch_bounds__(256) void scan_partial(const int* __restrict__ cnt,
                                                    int* __restrict__ off,
                                                    int* __restrict__ chsum) {
    __shared__ int lds[8];
    int b = blockIdx.x, t = threadIdx.x;
    int base = b * 1024 + t * 4;
    int v[4];
    int s = 0;
#pragma unroll
    for (int i = 0; i < 4; ++i) {
        int idx = base + i;
        v[i] = (idx < N_NODES) ? cnt[idx] : 0;
        s += v[i];
    }
    int lane = t & 63, w = t >> 6;
    int ssum = s;
#pragma unroll
    for (int d = 1; d < 64; d <<= 1) {
        int o = __shfl_up(ssum, d, 64);
        if (lane >= d) ssum += o;
    }
    if (lane == 63) lds[w] = ssum;
    __syncthreads();
    if (t == 0) {
        int a = 0;
        for (int i = 0; i < 4; ++i) { int tmp = lds[i]; lds[i] = a; a += tmp; }
        lds[4] = a;
    }
    __syncthreads();
    int run = lds[w] + ssum - s;  // exclusive prefix for this thread's first elem
#pragma unroll
    for (int i = 0; i < 4; ++i) {
        int idx = base + i;
        if (idx < N_NODES) off[idx] = run;
        run += v[i];
    }
    if (t == 0) chsum[b] = lds[4];
}

__global__ void scan_chsum(int* chsum) {
    if (blockIdx.x == 0 && threadIdx.x == 0) {
        int a = 0;
        for (int i = 0; i < NCH; ++i) { int t = chsum[i]; chsum[i] = a; a += t; }
    }
}

__global__ void scan_add(int* __restrict__ off, const int* __restrict__ chsum,
                         int* __restrict__ cur) {
    int i = blockIdx.x * blockDim.x + threadIdx.x;
    if (i < N_NODES) {
        int o = off[i] + chsum[i >> 10];
        off[i] = o;
        cur[i] = o;
    }
    if (i == 0) off[N_NODES] = N_EDGES;
}

__global__ void bucket_kernel(const int* __restrict__ rows, const int* __restrict__ cols,
                              const float* __restrict__ vals, int* __restrict__ cur,
                              int2* __restrict__ csr) {
    int stride = gridDim.x * blockDim.x;
    for (int e = blockIdx.x * blockDim.x + threadIdx.x; e < N_EDGES; e += stride) {
        int r = rows[e];
        int p = atomicAdd(&cur[r], 1);
        csr[p] = make_int2(cols[e], __float_as_int(vals[e]));
    }
}

// ---------------- Gather: one wave per output row, no atomics ----------------
__global__ __launch_bounds__(256) void gather_kernel(const float* __restrict__ H,
                                                     const int* __restrict__ off,
                                                     const int2* __restrict__ csr,
                                                     float* __restrict__ out) {
    int wid = (int)((blockIdx.x * 256 + threadIdx.x) >> 6);  // row id
    int lane = threadIdx.x & 63;
    if (wid >= N_NODES) return;
    int s = off[wid], e = off[wid + 1];
    int j = lane * 2;
    float2 acc = {0.f, 0.f};
    int p = s;
    for (; p + 1 < e; p += 2) {
        int2 cv0 = csr[p];
        int2 cv1 = csr[p + 1];
        float v0 = __int_as_float(cv0.y);
        float v1 = __int_as_float(cv1.y);
        float2 h0 = *(const float2*)&H[(long long)cv0.x * DIM + j];
        float2 h1 = *(const float2*)&H[(long long)cv1.x * DIM + j];
        acc.x += v0 * h0.x; acc.y += v0 * h0.y;
        acc.x += v1 * h1.x; acc.y += v1 * h1.y;
    }
    if (p < e) {
        int2 cv = csr[p];
        float v = __int_as_float(cv.y);
        float2 h = *(const float2*)&H[(long long)cv.x * DIM + j];
        acc.x += v * h.x; acc.y += v * h.y;
    }
    *(float2*)&out[(long long)wid * DIM + j] = acc;
}

// ---------------- Fallback scatter (if workspace too small) ----------------
__global__ __launch_bounds__(256) void scatter_kernel(const float* __restrict__ H,
                                                      const int* __restrict__ rows,
                                                      const int* __restrict__ cols,
                                                      const float* __restrict__ vals,
                                                      float* __restrict__ out) {
    long long total = (long long)N_EDGES * 64;
    long long stride = (long long)gridDim.x * blockDim.x;
    for (long long idx = (long long)blockIdx.x * blockDim.x + threadIdx.x;
         idx < total; idx += stride) {
        int e = (int)(idx >> 6);
        int j = ((int)idx & 63) * 2;
        int r = rows[e];
        int c = cols[e];
        float v = vals[e];
        float2 h = *(const float2*)&H[(long long)c * DIM + j];
        float* op = &out[(long long)r * DIM + j];
        atomicAdd(op,     v * h.x);
        atomicAdd(op + 1, v * h.y);
    }
}

extern "C" void kernel_launch(void* const* d_in, const int* in_sizes, int n_in,
                              void* d_out, int out_size, void* d_ws, size_t ws_size,
                              hipStream_t stream) {
    const float* x    = (const float*)d_in[0];
    const float* oh   = (const float*)d_in[1];
    const float* W0   = (const float*)d_in[2];
    const float* W1   = (const float*)d_in[3];
    const float* W2   = (const float*)d_in[4];
    const int*   rows = (const int*)d_in[5];
    const int*   cols = (const int*)d_in[6];
    const float* vals = (const float*)d_in[7];
    float* out = (float*)d_out;

    // workspace layout
    char* p = (char*)d_ws;
    size_t oW    = 0;                                  // Wsum: 64 KB
    size_t oH    = oW + 64 * 1024;                     // H: 51.2 MB
    size_t oCnt  = oH + (size_t)N_NODES * DIM * 4;     // cnt: 400 KB
    size_t oOff  = oCnt + (size_t)(N_NODES + 24) * 4;  // off: 100001 ints
    size_t oCur  = oOff + (size_t)(N_NODES + 24) * 4;  // cur: 400 KB
    size_t oCh   = oCur + (size_t)(N_NODES + 24) * 4;  // chsum: NCH ints
    size_t oCsr  = oCh + 4096;                         // csr: 12.8 MB
    size_t total = oCsr + (size_t)N_EDGES * 8;

    float* Wsum = (float*)(p + oW);
    float* H    = (float*)(p + oH);

    // 1. Wsum
    wsum_kernel<<<(DIM * DIM + 255) / 256, 256, 0, stream>>>(W0, W1, W2, Wsum);
    // 2. H = x @ Wsum + one_hot_h
    gemm_kernel<<<N_NODES / GEMM_ROWS, 256, 0, stream>>>(x, oh, Wsum, H);

    if (ws_size < total) {
        // fallback: atomic scatter (previous round's path)
        hipMemsetAsync(d_out, 0, (size_t)out_size * sizeof(float), stream);
        scatter_kernel<<<8192, 256, 0, stream>>>(H, rows, cols, vals, out);
        return;
    }

    int*  cnt   = (int*)(p + oCnt);
    int*  off   = (int*)(p + oOff);
    int*  cur   = (int*)(p + oCur);
    int*  chsum = (int*)(p + oCh);
    int2* csr   = (int2*)(p + oCsr);

    // 3. build CSR
    hipMemsetAsync(cnt, 0, (size_t)N_NODES * 4, stream);
    hist_kernel<<<2048, 256, 0, stream>>>(rows, cnt);
    scan_partial<<<NCH, 256, 0, stream>>>(cnt, off, chsum);
    scan_chsum<<<1, 64, 0, stream>>>(chsum);
    scan_add<<<(N_NODES + 255) / 256, 256, 0, stream>>>(off, chsum, cur);
    bucket_kernel<<<2048, 256, 0, stream>>>(rows, cols, vals, cur, csr);

    // 4. gather (one wave per row, no atomics)
    gather_kernel<<<(N_NODES * 64 + 255) / 256, 256, 0, stream>>>(H, off, csr, out);
}

// Round 3
// 345.840 us; speedup vs baseline: 3.9863x; 1.1156x over previous
//
#include <hip/hip_runtime.h>
#include <hip/hip_bf16.h>

#define N_NODES 100000
#define N_EDGES 1600000
#define DIM 128
#define NCH 98     // ceil(N_NODES / 1024)
#define NPART 8
#define ROWS_PER_PART (N_NODES / NPART)  // 12500

// ---------------- Kernel 1: Wsum = W0 + W1 + W2 ----------------
__global__ void wsum_kernel(const float* __restrict__ W0, const float* __restrict__ W1,
                            const float* __restrict__ W2, float* __restrict__ Wsum) {
    int i = blockIdx.x * blockDim.x + threadIdx.x;
    if (i < DIM * DIM) Wsum[i] = W0[i] + W1[i] + W2[i];
}

// ---------------- Kernel 2: H = x @ Wsum + one_hot_h ----------------
#define GEMM_ROWS 32
__global__ __launch_bounds__(256) void gemm_kernel(const float* __restrict__ x,
                                                   const float* __restrict__ oh,
                                                   const float* __restrict__ Wsum,
                                                   float* __restrict__ H) {
    __shared__ float ws[DIM * DIM];        // 64 KB
    __shared__ float xs[GEMM_ROWS * DIM];  // 16 KB
    int tid = threadIdx.x;

    for (int i = tid; i < DIM * DIM / 4; i += 256)
        ((float4*)ws)[i] = ((const float4*)Wsum)[i];

    long long row0 = (long long)blockIdx.x * GEMM_ROWS;
    for (int i = tid; i < GEMM_ROWS * DIM / 4; i += 256)
        ((float4*)xs)[i] = ((const float4*)(x + row0 * DIM))[i];

    __syncthreads();

    int j  = (tid & 31) * 4;
    int r0 = (tid >> 5) * 4;

    float acc[4][4];
#pragma unroll
    for (int r = 0; r < 4; ++r) {
        float4 o = *(const float4*)&oh[(row0 + r0 + r) * DIM + j];
        acc[r][0] = o.x; acc[r][1] = o.y; acc[r][2] = o.z; acc[r][3] = o.w;
    }

    for (int k = 0; k < DIM; k += 4) {
        float4 wv[4];
#pragma unroll
        for (int kk = 0; kk < 4; ++kk)
            wv[kk] = *(const float4*)&ws[(k + kk) * DIM + j];
#pragma unroll
        for (int r = 0; r < 4; ++r) {
            float4 xv = *(const float4*)&xs[(r0 + r) * DIM + k];
            acc[r][0] += xv.x * wv[0].x; acc[r][1] += xv.x * wv[0].y;
            acc[r][2] += xv.x * wv[0].z; acc[r][3] += xv.x * wv[0].w;
            acc[r][0] += xv.y * wv[1].x; acc[r][1] += xv.y * wv[1].y;
            acc[r][2] += xv.y * wv[1].z; acc[r][3] += xv.y * wv[1].w;
            acc[r][0] += xv.z * wv[2].x; acc[r][1] += xv.z * wv[2].y;
            acc[r][2] += xv.z * wv[2].z; acc[r][3] += xv.z * wv[2].w;
            acc[r][0] += xv.w * wv[3].x; acc[r][1] += xv.w * wv[3].y;
            acc[r][2] += xv.w * wv[3].z; acc[r][3] += xv.w * wv[3].w;
        }
    }

#pragma unroll
    for (int r = 0; r < 4; ++r) {
        float4 o = {acc[r][0], acc[r][1], acc[r][2], acc[r][3]};
        *(float4*)&H[(row0 + r0 + r) * DIM + j] = o;
    }
}

// ---------------- CSR build ----------------
__global__ void hist_kernel(const int* __restrict__ rows, int* __restrict__ cnt) {
    int stride = gridDim.x * blockDim.x;
    for (int e = blockIdx.x * blockDim.x + threadIdx.x; e < N_EDGES; e += stride)
        atomicAdd(&cnt[rows[e]], 1);
}

__global__ __launch_bounds__(256) void scan_partial(const int* __restrict__ cnt,
                                                    int* __restrict__ off,
                                                    int* __restrict__ chsum) {
    __shared__ int lds[8];
    int b = blockIdx.x, t = threadIdx.x;
    int base = b * 1024 + t * 4;
    int v[4];
    int s = 0;
#pragma unroll
    for (int i = 0; i < 4; ++i) {
        int idx = base + i;
        v[i] = (idx < N_NODES) ? cnt[idx] : 0;
        s += v[i];
    }
    int lane = t & 63, w = t >> 6;
    int ssum = s;
#pragma unroll
    for (int d = 1; d < 64; d <<= 1) {
        int o = __shfl_up(ssum, d, 64);
        if (lane >= d) ssum += o;
    }
    if (lane == 63) lds[w] = ssum;
    __syncthreads();
    if (t == 0) {
        int a = 0;
        for (int i = 0; i < 4; ++i) { int tmp = lds[i]; lds[i] = a; a += tmp; }
        lds[4] = a;
    }
    __syncthreads();
    int run = lds[w] + ssum - s;
#pragma unroll
    for (int i = 0; i < 4; ++i) {
        int idx = base + i;
        if (idx < N_NODES) off[idx] = run;
        run += v[i];
    }
    if (t == 0) chsum[b] = lds[4];
}

__global__ void scan_chsum(int* chsum) {
    if (blockIdx.x == 0 && threadIdx.x == 0) {
        int a = 0;
        for (int i = 0; i < NCH; ++i) { int t = chsum[i]; chsum[i] = a; a += t; }
    }
}

__global__ void scan_add(int* __restrict__ off, const int* __restrict__ chsum,
                         int* __restrict__ cur) {
    int i = blockIdx.x * blockDim.x + threadIdx.x;
    if (i < N_NODES) {
        int o = off[i] + chsum[i >> 10];
        off[i] = o;
        cur[i] = o;
    }
    if (i == 0) off[N_NODES] = N_EDGES;
}

// Partitioned bucket: blocks with (blockIdx&7)==p keep only rows in partition p.
// With round-robin block->XCD dispatch, partition p's csr region (1.6MB) stays
// in one XCD's L2 -> lines accumulate ~8 entries before writeback (12.8MB vs 102MB).
__global__ __launch_bounds__(256) void bucket_part_kernel(const int* __restrict__ rows,
                                                          const int* __restrict__ cols,
                                                          const float* __restrict__ vals,
                                                          int* __restrict__ cur,
                                                          int2* __restrict__ csr) {
    int part = blockIdx.x & (NPART - 1);
    int g    = blockIdx.x >> 3;
    int nthr = (gridDim.x >> 3) * 256;
    int rlo  = part * ROWS_PER_PART;
    int rhi  = rlo + ROWS_PER_PART;
    for (int e = g * 256 + threadIdx.x; e < N_EDGES; e += nthr) {
        int r = rows[e];
        if (r < rlo || r >= rhi) continue;
        int p = atomicAdd(&cur[r], 1);
        csr[p] = make_int2(cols[e], __float_as_int(vals[e]));
    }
}

// ---------------- Gather: one wave per output row, no atomics ----------------
__global__ __launch_bounds__(256) void gather_kernel(const float* __restrict__ H,
                                                     const int* __restrict__ off,
                                                     const long long* __restrict__ csr,
                                                     float* __restrict__ out) {
    int wid = (int)((blockIdx.x * 256 + threadIdx.x) >> 6);
    int lane = threadIdx.x & 63;
    if (wid >= N_NODES) return;
    int s = off[wid], e = off[wid + 1];
    int j = lane * 2;
    float2 acc = {0.f, 0.f};
    int p = s;
    for (; p + 3 < e; p += 4) {
        long long cv0 = __builtin_nontemporal_load(&csr[p]);
        long long cv1 = __builtin_nontemporal_load(&csr[p + 1]);
        long long cv2 = __builtin_nontemporal_load(&csr[p + 2]);
        long long cv3 = __builtin_nontemporal_load(&csr[p + 3]);
        float2 h0 = *(const float2*)&H[(long long)(int)cv0 * DIM + j];
        float2 h1 = *(const float2*)&H[(long long)(int)cv1 * DIM + j];
        float2 h2 = *(const float2*)&H[(long long)(int)cv2 * DIM + j];
        float2 h3 = *(const float2*)&H[(long long)(int)cv3 * DIM + j];
        float v0 = __int_as_float((int)(cv0 >> 32));
        float v1 = __int_as_float((int)(cv1 >> 32));
        float v2 = __int_as_float((int)(cv2 >> 32));
        float v3 = __int_as_float((int)(cv3 >> 32));
        acc.x += v0 * h0.x; acc.y += v0 * h0.y;
        acc.x += v1 * h1.x; acc.y += v1 * h1.y;
        acc.x += v2 * h2.x; acc.y += v2 * h2.y;
        acc.x += v3 * h3.x; acc.y += v3 * h3.y;
    }
    for (; p < e; ++p) {
        long long cv = __builtin_nontemporal_load(&csr[p]);
        float v = __int_as_float((int)(cv >> 32));
        float2 h = *(const float2*)&H[(long long)(int)cv * DIM + j];
        acc.x += v * h.x; acc.y += v * h.y;
    }
    *(float2*)&out[(long long)wid * DIM + j] = acc;
}

// ---------------- Fallback scatter (if workspace too small) ----------------
__global__ __launch_bounds__(256) void scatter_kernel(const float* __restrict__ H,
                                                      const int* __restrict__ rows,
                                                      const int* __restrict__ cols,
                                                      const float* __restrict__ vals,
                                                      float* __restrict__ out) {
    long long total = (long long)N_EDGES * 64;
    long long stride = (long long)gridDim.x * blockDim.x;
    for (long long idx = (long long)blockIdx.x * blockDim.x + threadIdx.x;
         idx < total; idx += stride) {
        int e = (int)(idx >> 6);
        int j = ((int)idx & 63) * 2;
        int r = rows[e];
        int c = cols[e];
        float v = vals[e];
        float2 h = *(const float2*)&H[(long long)c * DIM + j];
        float* op = &out[(long long)r * DIM + j];
        atomicAdd(op,     v * h.x);
        atomicAdd(op + 1, v * h.y);
    }
}

extern "C" void kernel_launch(void* const* d_in, const int* in_sizes, int n_in,
                              void* d_out, int out_size, void* d_ws, size_t ws_size,
                              hipStream_t stream) {
    const float* x    = (const float*)d_in[0];
    const float* oh   = (const float*)d_in[1];
    const float* W0   = (const float*)d_in[2];
    const float* W1   = (const float*)d_in[3];
    const float* W2   = (const float*)d_in[4];
    const int*   rows = (const int*)d_in[5];
    const int*   cols = (const int*)d_in[6];
    const float* vals = (const float*)d_in[7];
    float* out = (float*)d_out;

    // workspace layout
    char* p = (char*)d_ws;
    size_t oW    = 0;                                  // Wsum: 64 KB
    size_t oH    = oW + 64 * 1024;                     // H: 51.2 MB
    size_t oCnt  = oH + (size_t)N_NODES * DIM * 4;     // cnt
    size_t oOff  = oCnt + (size_t)(N_NODES + 24) * 4;  // off
    size_t oCur  = oOff + (size_t)(N_NODES + 24) * 4;  // cur
    size_t oCh   = oCur + (size_t)(N_NODES + 24) * 4;  // chsum
    size_t oCsr  = oCh + 4096;                         // csr: 12.8 MB
    size_t total = oCsr + (size_t)N_EDGES * 8;

    float* Wsum = (float*)(p + oW);
    float* H    = (float*)(p + oH);

    wsum_kernel<<<(DIM * DIM + 255) / 256, 256, 0, stream>>>(W0, W1, W2, Wsum);
    gemm_kernel<<<N_NODES / GEMM_ROWS, 256, 0, stream>>>(x, oh, Wsum, H);

    if (ws_size < total) {
        hipMemsetAsync(d_out, 0, (size_t)out_size * sizeof(float), stream);
        scatter_kernel<<<8192, 256, 0, stream>>>(H, rows, cols, vals, out);
        return;
    }

    int*  cnt   = (int*)(p + oCnt);
    int*  off   = (int*)(p + oOff);
    int*  cur   = (int*)(p + oCur);
    int*  chsum = (int*)(p + oCh);
    int2* csr   = (int2*)(p + oCsr);

    hipMemsetAsync(cnt, 0, (size_t)N_NODES * 4, stream);
    hist_kernel<<<2048, 256, 0, stream>>>(rows, cnt);
    scan_partial<<<NCH, 256, 0, stream>>>(cnt, off, chsum);
    scan_chsum<<<1, 64, 0, stream>>>(chsum);
    scan_add<<<(N_NODES + 255) / 256, 256, 0, stream>>>(off, chsum, cur);
    bucket_part_kernel<<<2048, 256, 0, stream>>>(rows, cols, vals, cur, csr);

    gather_kernel<<<(N_NODES * 64 + 255) / 256, 256, 0, stream>>>(H, off,
                                                                  (const long long*)csr, out);
}

// Round 4
// 317.024 us; speedup vs baseline: 4.3486x; 1.0909x over previous
//
#include <hip/hip_runtime.h>
#include <hip/hip_bf16.h>

#define N_NODES 100000
#define N_EDGES 1600000
#define DIM 128
#define NCH 98     // ceil(N_NODES / 1024)
#define NPART 8
#define ROWS_PER_PART (N_NODES / NPART)  // 12500

typedef unsigned int uint_t;
typedef unsigned short ushort_t;

// fp32 -> bf16 round-to-nearest-even
__device__ inline ushort_t f2bf(float f) {
    uint_t u = __float_as_uint(f);
    uint_t r = (u + 0x7FFFu + ((u >> 16) & 1u)) >> 16;
    return (ushort_t)r;
}
__device__ inline float bf2f(uint_t lo16) { return __uint_as_float(lo16 << 16); }

// ---------------- Kernel 1: Wsum = W0 + W1 + W2 ----------------
__global__ void wsum_kernel(const float* __restrict__ W0, const float* __restrict__ W1,
                            const float* __restrict__ W2, float* __restrict__ Wsum) {
    int i = blockIdx.x * blockDim.x + threadIdx.x;
    if (i < DIM * DIM) Wsum[i] = W0[i] + W1[i] + W2[i];
}

// ---------------- Kernel 2: H(bf16) = x @ Wsum + one_hot_h ----------------
#define GEMM_ROWS 32
__global__ __launch_bounds__(256) void gemm_kernel(const float* __restrict__ x,
                                                   const float* __restrict__ oh,
                                                   const float* __restrict__ Wsum,
                                                   uint_t* __restrict__ H16) {
    __shared__ float ws[DIM * DIM];        // 64 KB
    __shared__ float xs[GEMM_ROWS * DIM];  // 16 KB
    int tid = threadIdx.x;

    for (int i = tid; i < DIM * DIM / 4; i += 256)
        ((float4*)ws)[i] = ((const float4*)Wsum)[i];

    long long row0 = (long long)blockIdx.x * GEMM_ROWS;
    for (int i = tid; i < GEMM_ROWS * DIM / 4; i += 256)
        ((float4*)xs)[i] = ((const float4*)(x + row0 * DIM))[i];

    __syncthreads();

    int j  = (tid & 31) * 4;
    int r0 = (tid >> 5) * 4;

    float acc[4][4];
#pragma unroll
    for (int r = 0; r < 4; ++r) {
        float4 o = *(const float4*)&oh[(row0 + r0 + r) * DIM + j];
        acc[r][0] = o.x; acc[r][1] = o.y; acc[r][2] = o.z; acc[r][3] = o.w;
    }

    for (int k = 0; k < DIM; k += 4) {
        float4 wv[4];
#pragma unroll
        for (int kk = 0; kk < 4; ++kk)
            wv[kk] = *(const float4*)&ws[(k + kk) * DIM + j];
#pragma unroll
        for (int r = 0; r < 4; ++r) {
            float4 xv = *(const float4*)&xs[(r0 + r) * DIM + k];
            acc[r][0] += xv.x * wv[0].x; acc[r][1] += xv.x * wv[0].y;
            acc[r][2] += xv.x * wv[0].z; acc[r][3] += xv.x * wv[0].w;
            acc[r][0] += xv.y * wv[1].x; acc[r][1] += xv.y * wv[1].y;
            acc[r][2] += xv.y * wv[1].z; acc[r][3] += xv.y * wv[1].w;
            acc[r][0] += xv.z * wv[2].x; acc[r][1] += xv.z * wv[2].y;
            acc[r][2] += xv.z * wv[2].z; acc[r][3] += xv.z * wv[2].w;
            acc[r][0] += xv.w * wv[3].x; acc[r][1] += xv.w * wv[3].y;
            acc[r][2] += xv.w * wv[3].z; acc[r][3] += xv.w * wv[3].w;
        }
    }

    // pack 4 cols -> uint2 (4 bf16), store at row*64 + j/2
#pragma unroll
    for (int r = 0; r < 4; ++r) {
        uint2 o;
        o.x = (uint_t)f2bf(acc[r][0]) | ((uint_t)f2bf(acc[r][1]) << 16);
        o.y = (uint_t)f2bf(acc[r][2]) | ((uint_t)f2bf(acc[r][3]) << 16);
        *(uint2*)&H16[(row0 + r0 + r) * (DIM / 2) + j / 2] = o;
    }
}

// ---------------- CSR build ----------------
__global__ void hist_kernel(const int* __restrict__ rows, int* __restrict__ cnt) {
    int stride = gridDim.x * blockDim.x * 4;
    for (int e = (blockIdx.x * blockDim.x + threadIdx.x) * 4; e < N_EDGES; e += stride) {
        int4 r4 = *(const int4*)&rows[e];
        atomicAdd(&cnt[r4.x], 1);
        atomicAdd(&cnt[r4.y], 1);
        atomicAdd(&cnt[r4.z], 1);
        atomicAdd(&cnt[r4.w], 1);
    }
}

__global__ __launch_bounds__(256) void scan_partial(const int* __restrict__ cnt,
                                                    int* __restrict__ off,
                                                    int* __restrict__ chsum) {
    __shared__ int lds[8];
    int b = blockIdx.x, t = threadIdx.x;
    int base = b * 1024 + t * 4;
    int v[4];
    int s = 0;
#pragma unroll
    for (int i = 0; i < 4; ++i) {
        int idx = base + i;
        v[i] = (idx < N_NODES) ? cnt[idx] : 0;
        s += v[i];
    }
    int lane = t & 63, w = t >> 6;
    int ssum = s;
#pragma unroll
    for (int d = 1; d < 64; d <<= 1) {
        int o = __shfl_up(ssum, d, 64);
        if (lane >= d) ssum += o;
    }
    if (lane == 63) lds[w] = ssum;
    __syncthreads();
    if (t == 0) {
        int a = 0;
        for (int i = 0; i < 4; ++i) { int tmp = lds[i]; lds[i] = a; a += tmp; }
        lds[4] = a;
    }
    __syncthreads();
    int run = lds[w] + ssum - s;
#pragma unroll
    for (int i = 0; i < 4; ++i) {
        int idx = base + i;
        if (idx < N_NODES) off[idx] = run;
        run += v[i];
    }
    if (t == 0) chsum[b] = lds[4];
}

__global__ void scan_chsum(int* chsum) {
    if (blockIdx.x == 0 && threadIdx.x == 0) {
        int a = 0;
        for (int i = 0; i < NCH; ++i) { int t = chsum[i]; chsum[i] = a; a += t; }
    }
}

__global__ void scan_add(int* __restrict__ off, const int* __restrict__ chsum,
                         int* __restrict__ cur) {
    int i = blockIdx.x * blockDim.x + threadIdx.x;
    if (i < N_NODES) {
        int o = off[i] + chsum[i >> 10];
        off[i] = o;
        cur[i] = o;
    }
    if (i == 0) off[N_NODES] = N_EDGES;
}

// Partitioned bucket: blocks with (blockIdx&7)==p keep only rows in partition p
// (keeps csr writes XCD-local -> no 64B-line write amplification).
__global__ __launch_bounds__(256) void bucket_part_kernel(const int* __restrict__ rows,
                                                          const int* __restrict__ cols,
                                                          const float* __restrict__ vals,
                                                          int* __restrict__ cur,
                                                          int2* __restrict__ csr) {
    int part = blockIdx.x & (NPART - 1);
    int g    = blockIdx.x >> 3;
    int nthr = (gridDim.x >> 3) * 256;
    int rlo  = part * ROWS_PER_PART;
    int rhi  = rlo + ROWS_PER_PART;
    for (int e = (g * 256 + threadIdx.x) * 4; e < N_EDGES; e += nthr * 4) {
        int4 r4 = *(const int4*)&rows[e];
#pragma unroll
        for (int i = 0; i < 4; ++i) {
            int r = (i == 0) ? r4.x : (i == 1) ? r4.y : (i == 2) ? r4.z : r4.w;
            if (r < rlo || r >= rhi) continue;
            int p = atomicAdd(&cur[r], 1);
            csr[p] = make_int2(cols[e + i], __float_as_int(vals[e + i]));
        }
    }
}

// ---------------- Gather: one wave per output row, bf16 H, no atomics ----------------
__global__ __launch_bounds__(256) void gather_kernel(const uint_t* __restrict__ H16,
                                                     const int* __restrict__ off,
                                                     const long long* __restrict__ csr,
                                                     float* __restrict__ out) {
    int wid = (int)((blockIdx.x * 256 + threadIdx.x) >> 6);
    int lane = threadIdx.x & 63;
    if (wid >= N_NODES) return;
    int s = off[wid], e = off[wid + 1];
    float2 acc = {0.f, 0.f};
    int p = s;
    for (; p + 3 < e; p += 4) {
        long long cv0 = __builtin_nontemporal_load(&csr[p]);
        long long cv1 = __builtin_nontemporal_load(&csr[p + 1]);
        long long cv2 = __builtin_nontemporal_load(&csr[p + 2]);
        long long cv3 = __builtin_nontemporal_load(&csr[p + 3]);
        uint_t h0 = H16[(long long)(int)cv0 * (DIM / 2) + lane];
        uint_t h1 = H16[(long long)(int)cv1 * (DIM / 2) + lane];
        uint_t h2 = H16[(long long)(int)cv2 * (DIM / 2) + lane];
        uint_t h3 = H16[(long long)(int)cv3 * (DIM / 2) + lane];
        float v0 = __int_as_float((int)(cv0 >> 32));
        float v1 = __int_as_float((int)(cv1 >> 32));
        float v2 = __int_as_float((int)(cv2 >> 32));
        float v3 = __int_as_float((int)(cv3 >> 32));
        acc.x += v0 * bf2f(h0 & 0xFFFFu); acc.y += v0 * bf2f(h0 >> 16);
        acc.x += v1 * bf2f(h1 & 0xFFFFu); acc.y += v1 * bf2f(h1 >> 16);
        acc.x += v2 * bf2f(h2 & 0xFFFFu); acc.y += v2 * bf2f(h2 >> 16);
        acc.x += v3 * bf2f(h3 & 0xFFFFu); acc.y += v3 * bf2f(h3 >> 16);
    }
    for (; p < e; ++p) {
        long long cv = __builtin_nontemporal_load(&csr[p]);
        float v = __int_as_float((int)(cv >> 32));
        uint_t h = H16[(long long)(int)cv * (DIM / 2) + lane];
        acc.x += v * bf2f(h & 0xFFFFu); acc.y += v * bf2f(h >> 16);
    }
    *(float2*)&out[(long long)wid * DIM + lane * 2] = acc;
}

extern "C" void kernel_launch(void* const* d_in, const int* in_sizes, int n_in,
                              void* d_out, int out_size, void* d_ws, size_t ws_size,
                              hipStream_t stream) {
    const float* x    = (const float*)d_in[0];
    const float* oh   = (const float*)d_in[1];
    const float* W0   = (const float*)d_in[2];
    const float* W1   = (const float*)d_in[3];
    const float* W2   = (const float*)d_in[4];
    const int*   rows = (const int*)d_in[5];
    const int*   cols = (const int*)d_in[6];
    const float* vals = (const float*)d_in[7];
    float* out = (float*)d_out;

    // workspace layout
    char* p = (char*)d_ws;
    size_t oW    = 0;                                  // Wsum: 64 KB
    size_t oH    = oW + 64 * 1024;                     // H bf16: 25.6 MB
    size_t oCnt  = oH + (size_t)N_NODES * DIM * 2;     // cnt
    size_t oOff  = oCnt + (size_t)(N_NODES + 24) * 4;  // off
    size_t oCur  = oOff + (size_t)(N_NODES + 24) * 4;  // cur
    size_t oCh   = oCur + (size_t)(N_NODES + 24) * 4;  // chsum
    size_t oCsr  = oCh + 4096;                         // csr: 12.8 MB
    size_t total = oCsr + (size_t)N_EDGES * 8;
    (void)total; (void)ws_size;

    float*  Wsum = (float*)(p + oW);
    uint_t* H16  = (uint_t*)(p + oH);
    int*  cnt   = (int*)(p + oCnt);
    int*  off   = (int*)(p + oOff);
    int*  cur   = (int*)(p + oCur);
    int*  chsum = (int*)(p + oCh);
    int2* csr   = (int2*)(p + oCsr);

    wsum_kernel<<<(DIM * DIM + 255) / 256, 256, 0, stream>>>(W0, W1, W2, Wsum);
    gemm_kernel<<<N_NODES / GEMM_ROWS, 256, 0, stream>>>(x, oh, Wsum, H16);

    hipMemsetAsync(cnt, 0, (size_t)N_NODES * 4, stream);
    hist_kernel<<<1024, 256, 0, stream>>>(rows, cnt);
    scan_partial<<<NCH, 256, 0, stream>>>(cnt, off, chsum);
    scan_chsum<<<1, 64, 0, stream>>>(chsum);
    scan_add<<<(N_NODES + 255) / 256, 256, 0, stream>>>(off, chsum, cur);
    bucket_part_kernel<<<2048, 256, 0, stream>>>(rows, cols, vals, cur, csr);

    gather_kernel<<<(N_NODES * 64 + 255) / 256, 256, 0, stream>>>(H16, off,
                                                                  (const long long*)csr, out);
}

// Round 6
// 301.631 us; speedup vs baseline: 4.5705x; 1.0510x over previous
//
#include <hip/hip_runtime.h>
#include <hip/hip_bf16.h>

#define N_NODES 100000
#define N_EDGES 1600000
#define DIM 128
#define NCH 98     // ceil(N_NODES / 1024)
#define NPART 8
#define ROWS_PER_PART (N_NODES / NPART)  // 12500

typedef unsigned int uint_t;
typedef unsigned short ushort_t;

// fp32 -> bf16 round-to-nearest-even
__device__ inline ushort_t f2bf(float f) {
    uint_t u = __float_as_uint(f);
    uint_t r = (u + 0x7FFFu + ((u >> 16) & 1u)) >> 16;
    return (ushort_t)r;
}
__device__ inline float bf2f(uint_t lo16) { return __uint_as_float(lo16 << 16); }

// nontemporal 16B int load (builtin rejects HIP_vector_type; use 2x long long)
__device__ inline int4 nt_load_int4(const int* p) {
    long long a = __builtin_nontemporal_load((const long long*)p);
    long long b = __builtin_nontemporal_load((const long long*)p + 1);
    int4 r;
    r.x = (int)a; r.y = (int)(a >> 32);
    r.z = (int)b; r.w = (int)(b >> 32);
    return r;
}

// ---------------- Kernel A: hist (blocks 0..1023) + wsum (blocks 1024..1087) ----
__global__ void hist_wsum_kernel(const int* __restrict__ rows, int* __restrict__ cnt,
                                 const float* __restrict__ W0, const float* __restrict__ W1,
                                 const float* __restrict__ W2, float* __restrict__ Wsum) {
    if (blockIdx.x < 1024) {
        int stride = 1024 * 256 * 4;
        for (int e = (blockIdx.x * 256 + threadIdx.x) * 4; e < N_EDGES; e += stride) {
            int4 r4 = nt_load_int4(&rows[e]);
            atomicAdd(&cnt[r4.x], 1);
            atomicAdd(&cnt[r4.y], 1);
            atomicAdd(&cnt[r4.z], 1);
            atomicAdd(&cnt[r4.w], 1);
        }
    } else {
        int i = (blockIdx.x - 1024) * 256 + threadIdx.x;  // 64 blocks * 256 = 16384
        if (i < DIM * DIM) Wsum[i] = W0[i] + W1[i] + W2[i];
    }
}

// ---------------- Kernel 2: H(bf16) = x @ Wsum + one_hot_h ----------------
#define GEMM_ROWS 32
__global__ __launch_bounds__(256) void gemm_kernel(const float* __restrict__ x,
                                                   const float* __restrict__ oh,
                                                   const float* __restrict__ Wsum,
                                                   uint_t* __restrict__ H16) {
    __shared__ float ws[DIM * DIM];        // 64 KB
    __shared__ float xs[GEMM_ROWS * DIM];  // 16 KB
    int tid = threadIdx.x;

    for (int i = tid; i < DIM * DIM / 4; i += 256)
        ((float4*)ws)[i] = ((const float4*)Wsum)[i];

    long long row0 = (long long)blockIdx.x * GEMM_ROWS;
    for (int i = tid; i < GEMM_ROWS * DIM / 4; i += 256)
        ((float4*)xs)[i] = ((const float4*)(x + row0 * DIM))[i];

    __syncthreads();

    int j  = (tid & 31) * 4;
    int r0 = (tid >> 5) * 4;

    float acc[4][4];
#pragma unroll
    for (int r = 0; r < 4; ++r) {
        float4 o = *(const float4*)&oh[(row0 + r0 + r) * DIM + j];
        acc[r][0] = o.x; acc[r][1] = o.y; acc[r][2] = o.z; acc[r][3] = o.w;
    }

    for (int k = 0; k < DIM; k += 4) {
        float4 wv[4];
#pragma unroll
        for (int kk = 0; kk < 4; ++kk)
            wv[kk] = *(const float4*)&ws[(k + kk) * DIM + j];
#pragma unroll
        for (int r = 0; r < 4; ++r) {
            float4 xv = *(const float4*)&xs[(r0 + r) * DIM + k];
            acc[r][0] += xv.x * wv[0].x; acc[r][1] += xv.x * wv[0].y;
            acc[r][2] += xv.x * wv[0].z; acc[r][3] += xv.x * wv[0].w;
            acc[r][0] += xv.y * wv[1].x; acc[r][1] += xv.y * wv[1].y;
            acc[r][2] += xv.y * wv[1].z; acc[r][3] += xv.y * wv[1].w;
            acc[r][0] += xv.z * wv[2].x; acc[r][1] += xv.z * wv[2].y;
            acc[r][2] += xv.z * wv[2].z; acc[r][3] += xv.z * wv[2].w;
            acc[r][0] += xv.w * wv[3].x; acc[r][1] += xv.w * wv[3].y;
            acc[r][2] += xv.w * wv[3].z; acc[r][3] += xv.w * wv[3].w;
        }
    }

#pragma unroll
    for (int r = 0; r < 4; ++r) {
        uint2 o;
        o.x = (uint_t)f2bf(acc[r][0]) | ((uint_t)f2bf(acc[r][1]) << 16);
        o.y = (uint_t)f2bf(acc[r][2]) | ((uint_t)f2bf(acc[r][3]) << 16);
        *(uint2*)&H16[(row0 + r0 + r) * (DIM / 2) + j / 2] = o;
    }
}

// ---------------- CSR scan ----------------
__global__ __launch_bounds__(256) void scan_partial(const int* __restrict__ cnt,
                                                    int* __restrict__ off,
                                                    int* __restrict__ chsum) {
    __shared__ int lds[8];
    int b = blockIdx.x, t = threadIdx.x;
    int base = b * 1024 + t * 4;
    int v[4];
    int s = 0;
#pragma unroll
    for (int i = 0; i < 4; ++i) {
        int idx = base + i;
        v[i] = (idx < N_NODES) ? cnt[idx] : 0;
        s += v[i];
    }
    int lane = t & 63, w = t >> 6;
    int ssum = s;
#pragma unroll
    for (int d = 1; d < 64; d <<= 1) {
        int o = __shfl_up(ssum, d, 64);
        if (lane >= d) ssum += o;
    }
    if (lane == 63) lds[w] = ssum;
    __syncthreads();
    if (t == 0) {
        int a = 0;
        for (int i = 0; i < 4; ++i) { int tmp = lds[i]; lds[i] = a; a += tmp; }
        lds[4] = a;
    }
    __syncthreads();
    int run = lds[w] + ssum - s;
#pragma unroll
    for (int i = 0; i < 4; ++i) {
        int idx = base + i;
        if (idx < N_NODES) off[idx] = run;
        run += v[i];
    }
    if (t == 0) chsum[b] = lds[4];
}

// one-wave parallel exclusive scan of NCH=98 chunk sums (2 per lane)
__global__ void scan_chsum(int* chsum) {
    int lane = threadIdx.x & 63;
    int i0 = lane * 2, i1 = lane * 2 + 1;
    int v0 = (i0 < NCH) ? chsum[i0] : 0;
    int v1 = (i1 < NCH) ? chsum[i1] : 0;
    int pair = v0 + v1;
    int incl = pair;
#pragma unroll
    for (int d = 1; d < 64; d <<= 1) {
        int o = __shfl_up(incl, d, 64);
        if (lane >= d) incl += o;
    }
    int excl = incl - pair;
    if (i0 < NCH) chsum[i0] = excl;
    if (i1 < NCH) chsum[i1] = excl + v0;
}

__global__ void scan_add(int* __restrict__ off, const int* __restrict__ chsum,
                         int* __restrict__ cur) {
    int i = blockIdx.x * blockDim.x + threadIdx.x;
    if (i < N_NODES) {
        int o = off[i] + chsum[i >> 10];
        off[i] = o;
        cur[i] = o;
    }
    if (i == 0) off[N_NODES] = N_EDGES;
}

// Partitioned bucket: (blockIdx&7)==p keeps rows in partition p (XCD-local csr writes)
__global__ __launch_bounds__(256) void bucket_part_kernel(const int* __restrict__ rows,
                                                          const int* __restrict__ cols,
                                                          const float* __restrict__ vals,
                                                          int* __restrict__ cur,
                                                          int2* __restrict__ csr) {
    int part = blockIdx.x & (NPART - 1);
    int g    = blockIdx.x >> 3;
    int nthr = (gridDim.x >> 3) * 256;
    int rlo  = part * ROWS_PER_PART;
    int rhi  = rlo + ROWS_PER_PART;
    for (int e = (g * 256 + threadIdx.x) * 4; e < N_EDGES; e += nthr * 4) {
        int4 r4 = nt_load_int4(&rows[e]);
#pragma unroll
        for (int i = 0; i < 4; ++i) {
            int r = (i == 0) ? r4.x : (i == 1) ? r4.y : (i == 2) ? r4.z : r4.w;
            if (r < rlo || r >= rhi) continue;
            int p = atomicAdd(&cur[r], 1);
            csr[p] = make_int2(cols[e + i], __float_as_int(vals[e + i]));
        }
    }
}

// ---------------- Gather: 4 rows per wave, 16 lanes/row, uint4 loads ----------------
__global__ __launch_bounds__(256) void gather_kernel(const uint_t* __restrict__ H16,
                                                     const int* __restrict__ off,
                                                     const long long* __restrict__ csr,
                                                     float* __restrict__ out) {
    int tid  = threadIdx.x;
    int wave = tid >> 6;
    int lane = tid & 63;
    int grp  = lane >> 4;   // 0..3: which row within the wave
    int il   = lane & 15;   // lane within 16-lane group
    int wid  = blockIdx.x * 16 + wave * 4 + grp;  // row id (grid sized exactly)

    int s = off[wid], e = off[wid + 1];
    float acc[8] = {0.f, 0.f, 0.f, 0.f, 0.f, 0.f, 0.f, 0.f};

    int p = s;
    for (; p + 3 < e; p += 4) {
        long long cv0 = __builtin_nontemporal_load(&csr[p]);
        long long cv1 = __builtin_nontemporal_load(&csr[p + 1]);
        long long cv2 = __builtin_nontemporal_load(&csr[p + 2]);
        long long cv3 = __builtin_nontemporal_load(&csr[p + 3]);
        uint4 h0 = *(const uint4*)&H16[(long long)(int)cv0 * (DIM / 2) + il * 4];
        uint4 h1 = *(const uint4*)&H16[(long long)(int)cv1 * (DIM / 2) + il * 4];
        uint4 h2 = *(const uint4*)&H16[(long long)(int)cv2 * (DIM / 2) + il * 4];
        uint4 h3 = *(const uint4*)&H16[(long long)(int)cv3 * (DIM / 2) + il * 4];
        float v0 = __int_as_float((int)(cv0 >> 32));
        float v1 = __int_as_float((int)(cv1 >> 32));
        float v2 = __int_as_float((int)(cv2 >> 32));
        float v3 = __int_as_float((int)(cv3 >> 32));
#define ACC8(h, v)                                                        \
        acc[0] += (v) * bf2f((h).x & 0xFFFFu); acc[1] += (v) * bf2f((h).x >> 16); \
        acc[2] += (v) * bf2f((h).y & 0xFFFFu); acc[3] += (v) * bf2f((h).y >> 16); \
        acc[4] += (v) * bf2f((h).z & 0xFFFFu); acc[5] += (v) * bf2f((h).z >> 16); \
        acc[6] += (v) * bf2f((h).w & 0xFFFFu); acc[7] += (v) * bf2f((h).w >> 16);
        ACC8(h0, v0) ACC8(h1, v1) ACC8(h2, v2) ACC8(h3, v3)
    }
    for (; p < e; ++p) {
        long long cv = __builtin_nontemporal_load(&csr[p]);
        float v = __int_as_float((int)(cv >> 32));
        uint4 h = *(const uint4*)&H16[(long long)(int)cv * (DIM / 2) + il * 4];
        ACC8(h, v)
    }
#undef ACC8

    float* op = &out[(long long)wid * DIM + il * 8];
    float4 o0 = {acc[0], acc[1], acc[2], acc[3]};
    float4 o1 = {acc[4], acc[5], acc[6], acc[7]};
    *(float4*)op       = o0;
    *(float4*)(op + 4) = o1;
}

extern "C" void kernel_launch(void* const* d_in, const int* in_sizes, int n_in,
                              void* d_out, int out_size, void* d_ws, size_t ws_size,
                              hipStream_t stream) {
    const float* x    = (const float*)d_in[0];
    const float* oh   = (const float*)d_in[1];
    const float* W0   = (const float*)d_in[2];
    const float* W1   = (const float*)d_in[3];
    const float* W2   = (const float*)d_in[4];
    const int*   rows = (const int*)d_in[5];
    const int*   cols = (const int*)d_in[6];
    const float* vals = (const float*)d_in[7];
    float* out = (float*)d_out;

    // workspace layout
    char* p = (char*)d_ws;
    size_t oW    = 0;                                  // Wsum: 64 KB
    size_t oH    = oW + 64 * 1024;                     // H bf16: 25.6 MB
    size_t oCnt  = oH + (size_t)N_NODES * DIM * 2;     // cnt
    size_t oOff  = oCnt + (size_t)(N_NODES + 24) * 4;  // off
    size_t oCur  = oOff + (size_t)(N_NODES + 24) * 4;  // cur
    size_t oCh   = oCur + (size_t)(N_NODES + 24) * 4;  // chsum
    size_t oCsr  = oCh + 4096;                         // csr: 12.8 MB

    float*  Wsum = (float*)(p + oW);
    uint_t* H16  = (uint_t*)(p + oH);
    int*  cnt   = (int*)(p + oCnt);
    int*  off   = (int*)(p + oOff);
    int*  cur   = (int*)(p + oCur);
    int*  chsum = (int*)(p + oCh);
    int2* csr   = (int2*)(p + oCsr);

    (void)hipMemsetAsync(cnt, 0, (size_t)N_NODES * 4, stream);
    hist_wsum_kernel<<<1088, 256, 0, stream>>>(rows, cnt, W0, W1, W2, Wsum);
    gemm_kernel<<<N_NODES / GEMM_ROWS, 256, 0, stream>>>(x, oh, Wsum, H16);
    scan_partial<<<NCH, 256, 0, stream>>>(cnt, off, chsum);
    scan_chsum<<<1, 64, 0, stream>>>(chsum);
    scan_add<<<(N_NODES + 255) / 256, 256, 0, stream>>>(off, chsum, cur);
    bucket_part_kernel<<<4096, 256, 0, stream>>>(rows, cols, vals, cur, csr);

    // 100000 rows / 16 rows-per-block = 6250 blocks exactly
    gather_kernel<<<N_NODES / 16, 256, 0, stream>>>(H16, off, (const long long*)csr, out);
}

// Round 7
// 299.335 us; speedup vs baseline: 4.6056x; 1.0077x over previous
//
#include <hip/hip_runtime.h>
#include <hip/hip_bf16.h>

#define N_NODES 100000
#define N_EDGES 1600000
#define DIM 128
#define NCH 98     // ceil(N_NODES / 1024)
#define NPART 8
#define ROWS_PER_PART (N_NODES / NPART)  // 12500

// fused kernel geometry: 512 bucket groups + 391 gemm groups, 8 blocks each
#define BUCKET_GROUPS 512
#define GEMM_VBLOCKS  3125
#define GEMM_GROUPS   391
#define GG2           782            // 2*GEMM_GROUPS (interleave span)
#define TOTAL_GROUPS  903            // BUCKET_GROUPS + GEMM_GROUPS

typedef unsigned int uint_t;
typedef unsigned short ushort_t;
typedef float f32x4 __attribute__((ext_vector_type(4)));

// fp32 -> bf16 round-to-nearest-even
__device__ inline ushort_t f2bf(float f) {
    uint_t u = __float_as_uint(f);
    uint_t r = (u + 0x7FFFu + ((u >> 16) & 1u)) >> 16;
    return (ushort_t)r;
}
__device__ inline float bf2f(uint_t lo16) { return __uint_as_float(lo16 << 16); }

// nontemporal 16B int load (builtin rejects HIP_vector_type; use 2x long long)
__device__ inline int4 nt_load_int4(const int* p) {
    long long a = __builtin_nontemporal_load((const long long*)p);
    long long b = __builtin_nontemporal_load((const long long*)p + 1);
    int4 r;
    r.x = (int)a; r.y = (int)(a >> 32);
    r.z = (int)b; r.w = (int)(b >> 32);
    return r;
}

// ---------------- Kernel A: hist (blocks 0..1023) + wsum (blocks 1024..1087) ----
__global__ void hist_wsum_kernel(const int* __restrict__ rows, int* __restrict__ cnt,
                                 const float* __restrict__ W0, const float* __restrict__ W1,
                                 const float* __restrict__ W2, float* __restrict__ Wsum) {
    if (blockIdx.x < 1024) {
        int stride = 1024 * 256 * 4;
        for (int e = (blockIdx.x * 256 + threadIdx.x) * 4; e < N_EDGES; e += stride) {
            int4 r4 = nt_load_int4(&rows[e]);
            atomicAdd(&cnt[r4.x], 1);
            atomicAdd(&cnt[r4.y], 1);
            atomicAdd(&cnt[r4.z], 1);
            atomicAdd(&cnt[r4.w], 1);
        }
    } else {
        int i = (blockIdx.x - 1024) * 256 + threadIdx.x;
        if (i < DIM * DIM) Wsum[i] = W0[i] + W1[i] + W2[i];
    }
}

// ---------------- CSR scan ----------------
__global__ __launch_bounds__(256) void scan_partial(const int* __restrict__ cnt,
                                                    int* __restrict__ off,
                                                    int* __restrict__ chsum) {
    __shared__ int lds[8];
    int b = blockIdx.x, t = threadIdx.x;
    int base = b * 1024 + t * 4;
    int v[4];
    int s = 0;
#pragma unroll
    for (int i = 0; i < 4; ++i) {
        int idx = base + i;
        v[i] = (idx < N_NODES) ? cnt[idx] : 0;
        s += v[i];
    }
    int lane = t & 63, w = t >> 6;
    int ssum = s;
#pragma unroll
    for (int d = 1; d < 64; d <<= 1) {
        int o = __shfl_up(ssum, d, 64);
        if (lane >= d) ssum += o;
    }
    if (lane == 63) lds[w] = ssum;
    __syncthreads();
    if (t == 0) {
        int a = 0;
        for (int i = 0; i < 4; ++i) { int tmp = lds[i]; lds[i] = a; a += tmp; }
        lds[4] = a;
    }
    __syncthreads();
    int run = lds[w] + ssum - s;
#pragma unroll
    for (int i = 0; i < 4; ++i) {
        int idx = base + i;
        if (idx < N_NODES) off[idx] = run;
        run += v[i];
    }
    if (t == 0) chsum[b] = lds[4];  // raw chunk sum (scanned in scan_add2)
}

// scan_add2: folds the chunk-sum exclusive scan (was its own launch) into the
// add pass. chsum[] is read-only here (raw sums from scan_partial).
__global__ __launch_bounds__(256) void scan_add2(int* __restrict__ off,
                                                 const int* __restrict__ chsum,
                                                 int* __restrict__ cur) {
    __shared__ int chpre[NCH + 2];
    int t = threadIdx.x;
    if (t < 64) {
        int i0 = t * 2, i1 = t * 2 + 1;
        int v0 = (i0 < NCH) ? chsum[i0] : 0;
        int v1 = (i1 < NCH) ? chsum[i1] : 0;
        int pair = v0 + v1;
        int incl = pair;
#pragma unroll
        for (int d = 1; d < 64; d <<= 1) {
            int o = __shfl_up(incl, d, 64);
            if (t >= d) incl += o;
        }
        int excl = incl - pair;
        if (i0 < NCH) chpre[i0] = excl;
        if (i1 < NCH) chpre[i1] = excl + v0;
    }
    __syncthreads();
    int i = blockIdx.x * blockDim.x + t;
    if (i < N_NODES) {
        int o = off[i] + chpre[i >> 10];
        off[i] = o;
        cur[i] = o;
    }
    if (i == 0) off[N_NODES] = N_EDGES;
}

// ---------------- Fused: bucket (XCD-partitioned) || gemm (k-tiled, 32KB LDS) ----
// Interleave roles in groups of 8 blocks so bucket partition == blockIdx&7 == XCD.
__global__ __launch_bounds__(256) void fused_bucket_gemm(
        const int* __restrict__ rows, const int* __restrict__ cols,
        const float* __restrict__ vals, int* __restrict__ cur, int2* __restrict__ csr,
        const float* __restrict__ x, const float* __restrict__ oh,
        const float* __restrict__ Wsum, uint_t* __restrict__ H16) {
    __shared__ float ws[32 * DIM];        // 16 KB (k-tile of Wsum)
    __shared__ float xs[32 * DIM];        // 16 KB (32 x-rows)
    int g   = blockIdx.x >> 3;
    int sub = blockIdx.x & 7;
    bool is_gemm = (g < GG2) && (g & 1);

    if (is_gemm) {
        int gi = (g >> 1) * 8 + sub;
        if (gi >= GEMM_VBLOCKS) return;
        int tid = threadIdx.x;
        long long row0 = (long long)gi * 32;

        for (int i = tid; i < 32 * DIM / 4; i += 256)
            ((float4*)xs)[i] = ((const float4*)(x + row0 * DIM))[i];

        int j  = (tid & 31) * 4;
        int r0 = (tid >> 5) * 4;

        float acc[4][4];
#pragma unroll
        for (int r = 0; r < 4; ++r) {
            float4 o = *(const float4*)&oh[(row0 + r0 + r) * DIM + j];
            acc[r][0] = o.x; acc[r][1] = o.y; acc[r][2] = o.z; acc[r][3] = o.w;
        }

        for (int kt = 0; kt < 4; ++kt) {
            __syncthreads();  // xs ready (kt=0) / prev ws consumers done
            for (int i = tid; i < 32 * DIM / 4; i += 256)
                ((float4*)ws)[i] = ((const float4*)(Wsum + kt * 32 * DIM))[i];
            __syncthreads();
#pragma unroll
            for (int k = 0; k < 32; k += 4) {
                float4 wv[4];
#pragma unroll
                for (int kk = 0; kk < 4; ++kk)
                    wv[kk] = *(const float4*)&ws[(k + kk) * DIM + j];
#pragma unroll
                for (int r = 0; r < 4; ++r) {
                    float4 xv = *(const float4*)&xs[(r0 + r) * DIM + kt * 32 + k];
                    acc[r][0] += xv.x * wv[0].x; acc[r][1] += xv.x * wv[0].y;
                    acc[r][2] += xv.x * wv[0].z; acc[r][3] += xv.x * wv[0].w;
                    acc[r][0] += xv.y * wv[1].x; acc[r][1] += xv.y * wv[1].y;
                    acc[r][2] += xv.y * wv[1].z; acc[r][3] += xv.y * wv[1].w;
                    acc[r][0] += xv.z * wv[2].x; acc[r][1] += xv.z * wv[2].y;
                    acc[r][2] += xv.z * wv[2].z; acc[r][3] += xv.z * wv[2].w;
                    acc[r][0] += xv.w * wv[3].x; acc[r][1] += xv.w * wv[3].y;
                    acc[r][2] += xv.w * wv[3].z; acc[r][3] += xv.w * wv[3].w;
                }
            }
        }

#pragma unroll
        for (int r = 0; r < 4; ++r) {
            uint2 o;
            o.x = (uint_t)f2bf(acc[r][0]) | ((uint_t)f2bf(acc[r][1]) << 16);
            o.y = (uint_t)f2bf(acc[r][2]) | ((uint_t)f2bf(acc[r][3]) << 16);
            *(uint2*)&H16[(row0 + r0 + r) * (DIM / 2) + j / 2] = o;
        }
    } else {
        int bg = (g < GG2) ? (g >> 1) : (GEMM_GROUPS + (g - GG2));  // 0..511
        int part = sub;                       // == XCD (round-robin assumption)
        int rlo = part * ROWS_PER_PART;
        int rhi = rlo + ROWS_PER_PART;
        int nthr4 = BUCKET_GROUPS * 256 * 4;
        for (int e = (bg * 256 + threadIdx.x) * 4; e < N_EDGES; e += nthr4) {
            int4 r4 = nt_load_int4(&rows[e]);
#pragma unroll
            for (int i = 0; i < 4; ++i) {
                int r = (i == 0) ? r4.x : (i == 1) ? r4.y : (i == 2) ? r4.z : r4.w;
                if (r < rlo || r >= rhi) continue;
                // NT reads: keep streaming data out of L2 so dirty csr lines
                // survive until fully packed (kills 8x writeback amplification)
                int   c = __builtin_nontemporal_load(&cols[e + i]);
                float v = __builtin_nontemporal_load(&vals[e + i]);
                int ppos = atomicAdd(&cur[r], 1);
                csr[ppos] = make_int2(c, __float_as_int(v));
            }
        }
    }
}

// ---------------- Gather: 4 rows per wave, 16 lanes/row, uint4 loads ----------------
__global__ __launch_bounds__(256) void gather_kernel(const uint_t* __restrict__ H16,
                                                     const int* __restrict__ off,
                                                     const long long* __restrict__ csr,
                                                     float* __restrict__ out) {
    int tid  = threadIdx.x;
    int wave = tid >> 6;
    int lane = tid & 63;
    int grp  = lane >> 4;   // 0..3: which row within the wave
    int il   = lane & 15;   // lane within 16-lane group
    int wid  = blockIdx.x * 16 + wave * 4 + grp;

    int s = off[wid], e = off[wid + 1];
    float acc[8] = {0.f, 0.f, 0.f, 0.f, 0.f, 0.f, 0.f, 0.f};

    int p = s;
    for (; p + 3 < e; p += 4) {
        long long cv0 = __builtin_nontemporal_load(&csr[p]);
        long long cv1 = __builtin_nontemporal_load(&csr[p + 1]);
        long long cv2 = __builtin_nontemporal_load(&csr[p + 2]);
        long long cv3 = __builtin_nontemporal_load(&csr[p + 3]);
        uint4 h0 = *(const uint4*)&H16[(long long)(int)cv0 * (DIM / 2) + il * 4];
        uint4 h1 = *(const uint4*)&H16[(long long)(int)cv1 * (DIM / 2) + il * 4];
        uint4 h2 = *(const uint4*)&H16[(long long)(int)cv2 * (DIM / 2) + il * 4];
        uint4 h3 = *(const uint4*)&H16[(long long)(int)cv3 * (DIM / 2) + il * 4];
        float v0 = __int_as_float((int)(cv0 >> 32));
        float v1 = __int_as_float((int)(cv1 >> 32));
        float v2 = __int_as_float((int)(cv2 >> 32));
        float v3 = __int_as_float((int)(cv3 >> 32));
#define ACC8(h, v)                                                        \
        acc[0] += (v) * bf2f((h).x & 0xFFFFu); acc[1] += (v) * bf2f((h).x >> 16); \
        acc[2] += (v) * bf2f((h).y & 0xFFFFu); acc[3] += (v) * bf2f((h).y >> 16); \
        acc[4] += (v) * bf2f((h).z & 0xFFFFu); acc[5] += (v) * bf2f((h).z >> 16); \
        acc[6] += (v) * bf2f((h).w & 0xFFFFu); acc[7] += (v) * bf2f((h).w >> 16);
        ACC8(h0, v0) ACC8(h1, v1) ACC8(h2, v2) ACC8(h3, v3)
    }
    for (; p < e; ++p) {
        long long cv = __builtin_nontemporal_load(&csr[p]);
        float v = __int_as_float((int)(cv >> 32));
        uint4 h = *(const uint4*)&H16[(long long)(int)cv * (DIM / 2) + il * 4];
        ACC8(h, v)
    }
#undef ACC8

    float* op = &out[(long long)wid * DIM + il * 8];
    f32x4 o0 = {acc[0], acc[1], acc[2], acc[3]};
    f32x4 o1 = {acc[4], acc[5], acc[6], acc[7]};
    // NT stores: out is write-once streamed; keep L2 for H16 gathers
    __builtin_nontemporal_store(o0, (f32x4*)op);
    __builtin_nontemporal_store(o1, (f32x4*)(op + 4));
}

extern "C" void kernel_launch(void* const* d_in, const int* in_sizes, int n_in,
                              void* d_out, int out_size, void* d_ws, size_t ws_size,
                              hipStream_t stream) {
    const float* x    = (const float*)d_in[0];
    const float* oh   = (const float*)d_in[1];
    const float* W0   = (const float*)d_in[2];
    const float* W1   = (const float*)d_in[3];
    const float* W2   = (const float*)d_in[4];
    const int*   rows = (const int*)d_in[5];
    const int*   cols = (const int*)d_in[6];
    const float* vals = (const float*)d_in[7];
    float* out = (float*)d_out;

    // workspace layout
    char* p = (char*)d_ws;
    size_t oW    = 0;                                  // Wsum: 64 KB
    size_t oH    = oW + 64 * 1024;                     // H bf16: 25.6 MB
    size_t oCnt  = oH + (size_t)N_NODES * DIM * 2;     // cnt
    size_t oOff  = oCnt + (size_t)(N_NODES + 24) * 4;  // off
    size_t oCur  = oOff + (size_t)(N_NODES + 24) * 4;  // cur
    size_t oCh   = oCur + (size_t)(N_NODES + 24) * 4;  // chsum
    size_t oCsr  = oCh + 4096;                         // csr: 12.8 MB

    float*  Wsum = (float*)(p + oW);
    uint_t* H16  = (uint_t*)(p + oH);
    int*  cnt   = (int*)(p + oCnt);
    int*  off   = (int*)(p + oOff);
    int*  cur   = (int*)(p + oCur);
    int*  chsum = (int*)(p + oCh);
    int2* csr   = (int2*)(p + oCsr);

    (void)hipMemsetAsync(cnt, 0, (size_t)N_NODES * 4, stream);
    hist_wsum_kernel<<<1088, 256, 0, stream>>>(rows, cnt, W0, W1, W2, Wsum);
    scan_partial<<<NCH, 256, 0, stream>>>(cnt, off, chsum);
    scan_add2<<<(N_NODES + 255) / 256, 256, 0, stream>>>(off, chsum, cur);
    fused_bucket_gemm<<<TOTAL_GROUPS * 8, 256, 0, stream>>>(rows, cols, vals, cur, csr,
                                                            x, oh, Wsum, H16);
    gather_kernel<<<N_NODES / 16, 256, 0, stream>>>(H16, off, (const long long*)csr, out);
}

// Round 8
// 188.609 us; speedup vs baseline: 7.3094x; 1.5871x over previous
//
#include <hip/hip_runtime.h>
#include <hip/hip_bf16.h>

#define N_NODES 100000
#define N_EDGES 1600000
#define DIM 128

#define NBIN 256          // row partitions
#define RPP  391          // rows per partition (391*256 = 100096 >= 100000)
#define PCAP 8192         // slab capacity per partition (mean 6250, sigma ~79 -> +24 sigma)
#define P1_BLOCKS 256
#define CHUNK (N_EDGES / P1_BLOCKS)   // 6250 edges per pass-1 block

typedef unsigned int uint_t;
typedef unsigned short ushort_t;
typedef float f32x4 __attribute__((ext_vector_type(4)));

// fp32 -> bf16 round-to-nearest-even
__device__ inline ushort_t f2bf(float f) {
    uint_t u = __float_as_uint(f);
    uint_t r = (u + 0x7FFFu + ((u >> 16) & 1u)) >> 16;
    return (ushort_t)r;
}
__device__ inline float bf2f(uint_t lo16) { return __uint_as_float(lo16 << 16); }

// ---------------- Pass 1: coarse bin into 256 partition slabs (coalesced writes) ---
// blocks 0..255: binning; blocks 256..319: Wsum = W0+W1+W2
__global__ __launch_bounds__(256) void pass1_bin(
        const int* __restrict__ rows, const int* __restrict__ cols,
        const float* __restrict__ vals, int* __restrict__ psize,
        long long* __restrict__ slab,
        const float* __restrict__ W0, const float* __restrict__ W1,
        const float* __restrict__ W2, float* __restrict__ Wsum) {
    if (blockIdx.x >= P1_BLOCKS) {
        int i = (blockIdx.x - P1_BLOCKS) * 256 + threadIdx.x;
        if (i < DIM * DIM) Wsum[i] = W0[i] + W1[i] + W2[i];
        return;
    }
    __shared__ int hist[NBIN];
    __shared__ int binoff[NBIN];     // local exclusive offsets into ebuf
    __shared__ int resv[NBIN];       // absolute slab index of this block's segment
    __shared__ int curs[NBIN];       // scatter cursors
    __shared__ long long ebuf[CHUNK];  // 50 KB
    __shared__ int edest[CHUNK];       // 25 KB

    int t = threadIdx.x;
    int e0 = blockIdx.x * CHUNK;

    if (t < NBIN) hist[t] = 0;
    __syncthreads();

    for (int i = t; i < CHUNK; i += 256) {
        int r = rows[e0 + i];
        atomicAdd(&hist[r / RPP], 1);
    }
    __syncthreads();

    // exclusive scan of 256 bins: wave 0, 4 bins/lane
    if (t < 64) {
        int b = t * 4;
        int v0 = hist[b], v1 = hist[b + 1], v2 = hist[b + 2], v3 = hist[b + 3];
        int s = v0 + v1 + v2 + v3;
        int incl = s;
#pragma unroll
        for (int d = 1; d < 64; d <<= 1) {
            int o = __shfl_up(incl, d, 64);
            if (t >= d) incl += o;
        }
        int excl = incl - s;
        binoff[b]     = excl;
        binoff[b + 1] = excl + v0;
        binoff[b + 2] = excl + v0 + v1;
        binoff[b + 3] = excl + v0 + v1 + v2;
    }
    __syncthreads();

    if (t < NBIN) {
        int len = hist[t];
        int r = (len > 0) ? atomicAdd(&psize[t], len) : 0;
        resv[t] = t * PCAP + r;
        curs[t] = binoff[t];
    }
    __syncthreads();

    // scatter into LDS (re-read chunk; L2-hot)
    for (int i = t; i < CHUNK; i += 256) {
        int   r = rows[e0 + i];
        int   c = cols[e0 + i];
        float v = vals[e0 + i];
        int b  = r / RPP;
        int lr = r - b * RPP;
        int pos = atomicAdd(&curs[b], 1);
        uint_t key = ((uint_t)lr << 17) | (uint_t)c;   // lr<512 (9b), c<2^17
        ebuf[pos]  = ((long long)__float_as_int(v) << 32) | (long long)key;
        edest[pos] = resv[b] + (pos - binoff[b]);
    }
    __syncthreads();

    // flush: contiguous ~24-entry runs per bin -> near-coalesced
    for (int i = t; i < CHUNK; i += 256)
        slab[edest[i]] = ebuf[i];
}

// ---------------- pscan: partition bases (1 wave) + sentinel -------------------
__global__ void pscan(const int* __restrict__ psize, int* __restrict__ pbase,
                      int* __restrict__ off) {
    int lane = threadIdx.x & 63;
    int b = lane * 4;
    int v0 = min(psize[b], PCAP),     v1 = min(psize[b + 1], PCAP);
    int v2 = min(psize[b + 2], PCAP), v3 = min(psize[b + 3], PCAP);
    int s = v0 + v1 + v2 + v3;
    int incl = s;
#pragma unroll
    for (int d = 1; d < 64; d <<= 1) {
        int o = __shfl_up(incl, d, 64);
        if (lane >= d) incl += o;
    }
    int excl = incl - s;
    pbase[b]     = excl;
    pbase[b + 1] = excl + v0;
    pbase[b + 2] = excl + v0 + v1;
    pbase[b + 3] = excl + v0 + v1 + v2;
    if (lane == 0) off[N_NODES] = N_EDGES;
}

// ---------------- Pass 2: per-partition LDS counting sort, coalesced csr flush ---
__global__ __launch_bounds__(256) void pass2_sort(
        const long long* __restrict__ slab, const int* __restrict__ psize,
        const int* __restrict__ pbase, int* __restrict__ off,
        long long* __restrict__ csr) {
    __shared__ int cnt[RPP + 1];
    __shared__ int loff[RPP + 1];
    __shared__ int curs[RPP];
    __shared__ long long ebuf[PCAP];   // 64 KB

    int p = blockIdx.x, t = threadIdx.x;
    int n = min(psize[p], PCAP);
    int base = pbase[p];
    int rlo = p * RPP;
    int nrows = N_NODES - rlo; if (nrows > RPP) nrows = RPP;
    const long long* seg = slab + (long long)p * PCAP;

    for (int i = t; i < RPP + 1; i += 256) cnt[i] = 0;
    __syncthreads();

    for (int i = t; i < n; i += 256) {
        uint_t key = (uint_t)(seg[i] & 0xFFFFFFFFll);
        atomicAdd(&cnt[key >> 17], 1);
    }
    __syncthreads();

    // exclusive scan of RPP=391 counts: wave 0, 7/lane (64*7=448)
    if (t < 64) {
        int b7 = t * 7;
        int v[7]; int s = 0;
#pragma unroll
        for (int k = 0; k < 7; ++k) {
            int idx = b7 + k;
            v[k] = (idx < RPP) ? cnt[idx] : 0;
            s += v[k];
        }
        int incl = s;
#pragma unroll
        for (int d = 1; d < 64; d <<= 1) {
            int o = __shfl_up(incl, d, 64);
            if (t >= d) incl += o;
        }
        int run = incl - s;
#pragma unroll
        for (int k = 0; k < 7; ++k) {
            int idx = b7 + k;
            if (idx < RPP) loff[idx] = run;
            run += v[k];
        }
    }
    __syncthreads();

    for (int i = t; i < nrows; i += 256) {
        curs[i] = loff[i];
        off[rlo + i] = base + loff[i];
    }
    __syncthreads();

    // scatter into final order in LDS (re-read seg; L2/L3-hot)
    for (int i = t; i < n; i += 256) {
        long long ev = seg[i];
        uint_t key = (uint_t)(ev & 0xFFFFFFFFll);
        int lr = key >> 17;
        uint_t c = key & 0x1FFFFu;
        int pos = atomicAdd(&curs[lr], 1);
        ebuf[pos] = (long long)(((unsigned long long)ev & 0xFFFFFFFF00000000ull) | c);
    }
    __syncthreads();

    // fully-coalesced flush of the partition's csr segment
    for (int i = t; i < n; i += 256)
        __builtin_nontemporal_store(ebuf[i], &csr[base + i]);
}

// ---------------- Gemm: H(bf16) = x @ Wsum + one_hot_h (80KB LDS) ----------------
__global__ __launch_bounds__(256) void gemm_kernel(const float* __restrict__ x,
                                                   const float* __restrict__ oh,
                                                   const float* __restrict__ Wsum,
                                                   uint_t* __restrict__ H16) {
    __shared__ float ws[DIM * DIM];   // 64 KB
    __shared__ float xs[32 * DIM];    // 16 KB
    int tid = threadIdx.x;

    for (int i = tid; i < DIM * DIM / 4; i += 256)
        ((float4*)ws)[i] = ((const float4*)Wsum)[i];

    long long row0 = (long long)blockIdx.x * 32;
    for (int i = tid; i < 32 * DIM / 4; i += 256)
        ((float4*)xs)[i] = ((const float4*)(x + row0 * DIM))[i];

    __syncthreads();

    int j  = (tid & 31) * 4;
    int r0 = (tid >> 5) * 4;

    float acc[4][4];
#pragma unroll
    for (int r = 0; r < 4; ++r) {
        float4 o = *(const float4*)&oh[(row0 + r0 + r) * DIM + j];
        acc[r][0] = o.x; acc[r][1] = o.y; acc[r][2] = o.z; acc[r][3] = o.w;
    }

    for (int k = 0; k < DIM; k += 4) {
        float4 wv[4];
#pragma unroll
        for (int kk = 0; kk < 4; ++kk)
            wv[kk] = *(const float4*)&ws[(k + kk) * DIM + j];
#pragma unroll
        for (int r = 0; r < 4; ++r) {
            float4 xv = *(const float4*)&xs[(r0 + r) * DIM + k];
            acc[r][0] += xv.x * wv[0].x; acc[r][1] += xv.x * wv[0].y;
            acc[r][2] += xv.x * wv[0].z; acc[r][3] += xv.x * wv[0].w;
            acc[r][0] += xv.y * wv[1].x; acc[r][1] += xv.y * wv[1].y;
            acc[r][2] += xv.y * wv[1].z; acc[r][3] += xv.y * wv[1].w;
            acc[r][0] += xv.z * wv[2].x; acc[r][1] += xv.z * wv[2].y;
            acc[r][2] += xv.z * wv[2].z; acc[r][3] += xv.z * wv[2].w;
            acc[r][0] += xv.w * wv[3].x; acc[r][1] += xv.w * wv[3].y;
            acc[r][2] += xv.w * wv[3].z; acc[r][3] += xv.w * wv[3].w;
        }
    }

#pragma unroll
    for (int r = 0; r < 4; ++r) {
        uint2 o;
        o.x = (uint_t)f2bf(acc[r][0]) | ((uint_t)f2bf(acc[r][1]) << 16);
        o.y = (uint_t)f2bf(acc[r][2]) | ((uint_t)f2bf(acc[r][3]) << 16);
        *(uint2*)&H16[(row0 + r0 + r) * (DIM / 2) + j / 2] = o;
    }
}

// ---------------- Gather: 4 rows per wave, 16 lanes/row, uint4 loads ----------------
__global__ __launch_bounds__(256) void gather_kernel(const uint_t* __restrict__ H16,
                                                     const int* __restrict__ off,
                                                     const long long* __restrict__ csr,
                                                     float* __restrict__ out) {
    int tid  = threadIdx.x;
    int wave = tid >> 6;
    int lane = tid & 63;
    int grp  = lane >> 4;
    int il   = lane & 15;
    int wid  = blockIdx.x * 16 + wave * 4 + grp;

    int s = off[wid], e = off[wid + 1];
    float acc[8] = {0.f, 0.f, 0.f, 0.f, 0.f, 0.f, 0.f, 0.f};

    int p = s;
    for (; p + 3 < e; p += 4) {
        long long cv0 = __builtin_nontemporal_load(&csr[p]);
        long long cv1 = __builtin_nontemporal_load(&csr[p + 1]);
        long long cv2 = __builtin_nontemporal_load(&csr[p + 2]);
        long long cv3 = __builtin_nontemporal_load(&csr[p + 3]);
        uint4 h0 = *(const uint4*)&H16[(long long)(int)cv0 * (DIM / 2) + il * 4];
        uint4 h1 = *(const uint4*)&H16[(long long)(int)cv1 * (DIM / 2) + il * 4];
        uint4 h2 = *(const uint4*)&H16[(long long)(int)cv2 * (DIM / 2) + il * 4];
        uint4 h3 = *(const uint4*)&H16[(long long)(int)cv3 * (DIM / 2) + il * 4];
        float v0 = __int_as_float((int)(cv0 >> 32));
        float v1 = __int_as_float((int)(cv1 >> 32));
        float v2 = __int_as_float((int)(cv2 >> 32));
        float v3 = __int_as_float((int)(cv3 >> 32));
#define ACC8(h, v)                                                        \
        acc[0] += (v) * bf2f((h).x & 0xFFFFu); acc[1] += (v) * bf2f((h).x >> 16); \
        acc[2] += (v) * bf2f((h).y & 0xFFFFu); acc[3] += (v) * bf2f((h).y >> 16); \
        acc[4] += (v) * bf2f((h).z & 0xFFFFu); acc[5] += (v) * bf2f((h).z >> 16); \
        acc[6] += (v) * bf2f((h).w & 0xFFFFu); acc[7] += (v) * bf2f((h).w >> 16);
        ACC8(h0, v0) ACC8(h1, v1) ACC8(h2, v2) ACC8(h3, v3)
    }
    for (; p < e; ++p) {
        long long cv = __builtin_nontemporal_load(&csr[p]);
        float v = __int_as_float((int)(cv >> 32));
        uint4 h = *(const uint4*)&H16[(long long)(int)cv * (DIM / 2) + il * 4];
        ACC8(h, v)
    }
#undef ACC8

    float* op = &out[(long long)wid * DIM + il * 8];
    f32x4 o0 = {acc[0], acc[1], acc[2], acc[3]};
    f32x4 o1 = {acc[4], acc[5], acc[6], acc[7]};
    __builtin_nontemporal_store(o0, (f32x4*)op);
    __builtin_nontemporal_store(o1, (f32x4*)(op + 4));
}

extern "C" void kernel_launch(void* const* d_in, const int* in_sizes, int n_in,
                              void* d_out, int out_size, void* d_ws, size_t ws_size,
                              hipStream_t stream) {
    const float* x    = (const float*)d_in[0];
    const float* oh   = (const float*)d_in[1];
    const float* W0   = (const float*)d_in[2];
    const float* W1   = (const float*)d_in[3];
    const float* W2   = (const float*)d_in[4];
    const int*   rows = (const int*)d_in[5];
    const int*   cols = (const int*)d_in[6];
    const float* vals = (const float*)d_in[7];
    float* out = (float*)d_out;

    // workspace layout
    char* p = (char*)d_ws;
    size_t oW    = 0;                                   // Wsum: 64 KB
    size_t oH    = oW + 64 * 1024;                      // H bf16: 25.6 MB
    size_t oOff  = oH + (size_t)N_NODES * DIM * 2;      // off: N_NODES+1 (+pad)
    size_t oPs   = oOff + (size_t)(N_NODES + 32) * 4;   // psize: 256 ints
    size_t oPb   = oPs + 2048;                          // pbase: 257 ints
    size_t oSlab = oPb + 2048;                          // slabs: 256*8192*8B = 16.8 MB
    size_t oCsr  = oSlab + (size_t)NBIN * PCAP * 8;     // csr: 12.8 MB

    float*     Wsum  = (float*)(p + oW);
    uint_t*    H16   = (uint_t*)(p + oH);
    int*       off   = (int*)(p + oOff);
    int*       psize = (int*)(p + oPs);
    int*       pbase = (int*)(p + oPb);
    long long* slab  = (long long*)(p + oSlab);
    long long* csr   = (long long*)(p + oCsr);

    (void)hipMemsetAsync(psize, 0, NBIN * sizeof(int), stream);
    pass1_bin<<<P1_BLOCKS + 64, 256, 0, stream>>>(rows, cols, vals, psize, slab,
                                                  W0, W1, W2, Wsum);
    pscan<<<1, 64, 0, stream>>>(psize, pbase, off);
    gemm_kernel<<<N_NODES / 32, 256, 0, stream>>>(x, oh, Wsum, H16);
    pass2_sort<<<NBIN, 256, 0, stream>>>(slab, psize, pbase, off, csr);
    gather_kernel<<<N_NODES / 16, 256, 0, stream>>>(H16, off, csr, out);
}

// Round 9
// 164.875 us; speedup vs baseline: 8.3616x; 1.1439x over previous
//
#include <hip/hip_runtime.h>
#include <hip/hip_bf16.h>

#define N_NODES 100000
#define N_EDGES 1600000
#define DIM 128

#define NBIN 256          // row partitions
#define RPP  391          // rows per partition (391*256 = 100096 >= 100000)
#define PCAP 8192         // slab capacity per partition (mean 6250)
#define P1_BLOCKS 256
#define CHUNK (N_EDGES / P1_BLOCKS)   // 6250 edges per pass-1 block

typedef unsigned int uint_t;
typedef unsigned short ushort_t;
typedef float f32x4 __attribute__((ext_vector_type(4)));
typedef __bf16 bf16x8 __attribute__((ext_vector_type(8)));

// fp32 -> bf16 round-to-nearest-even (bit-exact, used for H16 store + WsumT build)
__device__ inline ushort_t f2bf(float f) {
    uint_t u = __float_as_uint(f);
    uint_t r = (u + 0x7FFFu + ((u >> 16) & 1u)) >> 16;
    return (ushort_t)r;
}
__device__ inline float bf2f(uint_t lo16) { return __uint_as_float(lo16 << 16); }

// ---------------- Pass 1: coarse bin into 256 partition slabs (coalesced writes) ---
// blocks 0..255: binning; blocks 256..319: WsumT16[m][k] = bf16(sum W[k][m])
__global__ __launch_bounds__(256) void pass1_bin(
        const int* __restrict__ rows, const int* __restrict__ cols,
        const float* __restrict__ vals, int* __restrict__ psize,
        long long* __restrict__ slab,
        const float* __restrict__ W0, const float* __restrict__ W1,
        const float* __restrict__ W2, ushort_t* __restrict__ WT) {
    if (blockIdx.x >= P1_BLOCKS) {
        int i = (blockIdx.x - P1_BLOCKS) * 256 + threadIdx.x;
        if (i < DIM * DIM) {
            int m = i & 127, k = i >> 7;        // consecutive threads -> consecutive m: coalesced reads
            float s = W0[k * DIM + m] + W1[k * DIM + m] + W2[k * DIM + m];
            WT[m * DIM + k] = f2bf(s);          // transposed bf16 (32 KB, L2-resident)
        }
        return;
    }
    __shared__ int hist[NBIN];
    __shared__ int binoff[NBIN];
    __shared__ int resv[NBIN];
    __shared__ int curs[NBIN];
    __shared__ long long ebuf[CHUNK];  // 50 KB
    __shared__ int edest[CHUNK];       // 25 KB

    int t = threadIdx.x;
    int e0 = blockIdx.x * CHUNK;

    if (t < NBIN) hist[t] = 0;
    __syncthreads();

    for (int i = t; i < CHUNK; i += 256) {
        int r = rows[e0 + i];
        atomicAdd(&hist[r / RPP], 1);
    }
    __syncthreads();

    if (t < 64) {
        int b = t * 4;
        int v0 = hist[b], v1 = hist[b + 1], v2 = hist[b + 2], v3 = hist[b + 3];
        int s = v0 + v1 + v2 + v3;
        int incl = s;
#pragma unroll
        for (int d = 1; d < 64; d <<= 1) {
            int o = __shfl_up(incl, d, 64);
            if (t >= d) incl += o;
        }
        int excl = incl - s;
        binoff[b]     = excl;
        binoff[b + 1] = excl + v0;
        binoff[b + 2] = excl + v0 + v1;
        binoff[b + 3] = excl + v0 + v1 + v2;
    }
    __syncthreads();

    if (t < NBIN) {
        int len = hist[t];
        int r = (len > 0) ? atomicAdd(&psize[t], len) : 0;
        resv[t] = t * PCAP + r;
        curs[t] = binoff[t];
    }
    __syncthreads();

    for (int i = t; i < CHUNK; i += 256) {
        int   r = rows[e0 + i];
        int   c = cols[e0 + i];
        float v = vals[e0 + i];
        int b  = r / RPP;
        int lr = r - b * RPP;
        int pos = atomicAdd(&curs[b], 1);
        uint_t key = ((uint_t)lr << 17) | (uint_t)c;
        ebuf[pos]  = ((long long)__float_as_int(v) << 32) | (long long)key;
        edest[pos] = resv[b] + (pos - binoff[b]);
    }
    __syncthreads();

    for (int i = t; i < CHUNK; i += 256)
        slab[edest[i]] = ebuf[i];
}

// ---------------- pscan: partition bases (1 wave) + sentinel -------------------
__global__ void pscan(const int* __restrict__ psize, int* __restrict__ pbase,
                      int* __restrict__ off) {
    int lane = threadIdx.x & 63;
    int b = lane * 4;
    int v0 = min(psize[b], PCAP),     v1 = min(psize[b + 1], PCAP);
    int v2 = min(psize[b + 2], PCAP), v3 = min(psize[b + 3], PCAP);
    int s = v0 + v1 + v2 + v3;
    int incl = s;
#pragma unroll
    for (int d = 1; d < 64; d <<= 1) {
        int o = __shfl_up(incl, d, 64);
        if (lane >= d) incl += o;
    }
    int excl = incl - s;
    pbase[b]     = excl;
    pbase[b + 1] = excl + v0;
    pbase[b + 2] = excl + v0 + v1;
    pbase[b + 3] = excl + v0 + v1 + v2;
    if (lane == 0) off[N_NODES] = N_EDGES;
}

// ---------------- Pass 2: per-partition LDS counting sort, coalesced csr flush ---
__global__ __launch_bounds__(256) void pass2_sort(
        const long long* __restrict__ slab, const int* __restrict__ psize,
        const int* __restrict__ pbase, int* __restrict__ off,
        long long* __restrict__ csr) {
    __shared__ int cnt[RPP + 1];
    __shared__ int loff[RPP + 1];
    __shared__ int curs[RPP];
    __shared__ long long ebuf[PCAP];   // 64 KB

    int p = blockIdx.x, t = threadIdx.x;
    int n = min(psize[p], PCAP);
    int base = pbase[p];
    int rlo = p * RPP;
    int nrows = N_NODES - rlo; if (nrows > RPP) nrows = RPP;
    const long long* seg = slab + (long long)p * PCAP;

    for (int i = t; i < RPP + 1; i += 256) cnt[i] = 0;
    __syncthreads();

    for (int i = t; i < n; i += 256) {
        uint_t key = (uint_t)(seg[i] & 0xFFFFFFFFll);
        atomicAdd(&cnt[key >> 17], 1);
    }
    __syncthreads();

    if (t < 64) {
        int b7 = t * 7;
        int v[7]; int s = 0;
#pragma unroll
        for (int k = 0; k < 7; ++k) {
            int idx = b7 + k;
            v[k] = (idx < RPP) ? cnt[idx] : 0;
            s += v[k];
        }
        int incl = s;
#pragma unroll
        for (int d = 1; d < 64; d <<= 1) {
            int o = __shfl_up(incl, d, 64);
            if (t >= d) incl += o;
        }
        int run = incl - s;
#pragma unroll
        for (int k = 0; k < 7; ++k) {
            int idx = b7 + k;
            if (idx < RPP) loff[idx] = run;
            run += v[k];
        }
    }
    __syncthreads();

    for (int i = t; i < nrows; i += 256) {
        curs[i] = loff[i];
        off[rlo + i] = base + loff[i];
    }
    __syncthreads();

    for (int i = t; i < n; i += 256) {
        long long ev = seg[i];
        uint_t key = (uint_t)(ev & 0xFFFFFFFFll);
        int lr = key >> 17;
        uint_t c = key & 0x1FFFFu;
        int pos = atomicAdd(&curs[lr], 1);
        ebuf[pos] = (long long)(((unsigned long long)ev & 0xFFFFFFFF00000000ull) | c);
    }
    __syncthreads();

    for (int i = t; i < n; i += 256)
        __builtin_nontemporal_store(ebuf[i], &csr[base + i]);
}

// ---------------- Gemm via MFMA: H(bf16) = x @ Wsum + one_hot_h -------------------
// Computes H^T fragments: A = WT (Wsum^T, bf16), B = x^T. D-lane layout then gives
// each lane 4 CONSECUTIVE H-columns of ONE H-row -> float4 oh load + uint2 H16 store.
// No LDS; WT (32 KB) stays cache-resident. 4 waves x 16 rows = 64 rows/block.
__global__ __launch_bounds__(256) void gemm_mfma(const float* __restrict__ x,
                                                 const float* __restrict__ oh,
                                                 const ushort_t* __restrict__ WT,
                                                 uint_t* __restrict__ H16) {
    int tid = threadIdx.x;
    int wv = tid >> 6, l = tid & 63;
    int lr = l & 15, kg = l >> 4;          // lane row / k-group
    int hr = blockIdx.x * 64 + wv * 16 + lr;
    int hr_c = (hr < N_NODES) ? hr : (N_NODES - 1);

    f32x4 acc[8] = {};
    const float* xrow = x + (size_t)hr_c * DIM;

#pragma unroll
    for (int s = 0; s < 4; ++s) {          // K slabs of 32
        float4 xa = *(const float4*)(xrow + s * 32 + kg * 8);
        float4 xb = *(const float4*)(xrow + s * 32 + kg * 8 + 4);
        union { bf16x8 v; __bf16 h[8]; } b;
        b.h[0] = (__bf16)xa.x; b.h[1] = (__bf16)xa.y;
        b.h[2] = (__bf16)xa.z; b.h[3] = (__bf16)xa.w;
        b.h[4] = (__bf16)xb.x; b.h[5] = (__bf16)xb.y;
        b.h[6] = (__bf16)xb.z; b.h[7] = (__bf16)xb.w;
#pragma unroll
        for (int mt = 0; mt < 8; ++mt) {   // H-col tiles
            bf16x8 a = *(const bf16x8*)&WT[(mt * 16 + lr) * DIM + s * 32 + kg * 8];
            acc[mt] = __builtin_amdgcn_mfma_f32_16x16x32_bf16(a, b.v, acc[mt], 0, 0, 0);
        }
    }

    if (hr < N_NODES) {
#pragma unroll
        for (int mt = 0; mt < 8; ++mt) {
            int c0 = mt * 16 + kg * 4;
            float4 o = *(const float4*)&oh[(size_t)hr * DIM + c0];
            float f0 = acc[mt].x + o.x, f1 = acc[mt].y + o.y;
            float f2 = acc[mt].z + o.z, f3 = acc[mt].w + o.w;
            uint2 pk;
            pk.x = (uint_t)f2bf(f0) | ((uint_t)f2bf(f1) << 16);
            pk.y = (uint_t)f2bf(f2) | ((uint_t)f2bf(f3) << 16);
            *(uint2*)&H16[(size_t)hr * (DIM / 2) + c0 / 2] = pk;
        }
    }
}

// ---------------- Gather: 4 rows per wave, 16 lanes/row, uint4 loads ----------------
__global__ __launch_bounds__(256) void gather_kernel(const uint_t* __restrict__ H16,
                                                     const int* __restrict__ off,
                                                     const long long* __restrict__ csr,
                                                     float* __restrict__ out) {
    int tid  = threadIdx.x;
    int wave = tid >> 6;
    int lane = tid & 63;
    int grp  = lane >> 4;
    int il   = lane & 15;
    int wid  = blockIdx.x * 16 + wave * 4 + grp;

    int s = off[wid], e = off[wid + 1];
    float acc[8] = {0.f, 0.f, 0.f, 0.f, 0.f, 0.f, 0.f, 0.f};

    int p = s;
    for (; p + 3 < e; p += 4) {
        long long cv0 = __builtin_nontemporal_load(&csr[p]);
        long long cv1 = __builtin_nontemporal_load(&csr[p + 1]);
        long long cv2 = __builtin_nontemporal_load(&csr[p + 2]);
        long long cv3 = __builtin_nontemporal_load(&csr[p + 3]);
        uint4 h0 = *(const uint4*)&H16[(long long)(int)(cv0 & 0x1FFFF) * (DIM / 2) + il * 4];
        uint4 h1 = *(const uint4*)&H16[(long long)(int)(cv1 & 0x1FFFF) * (DIM / 2) + il * 4];
        uint4 h2 = *(const uint4*)&H16[(long long)(int)(cv2 & 0x1FFFF) * (DIM / 2) + il * 4];
        uint4 h3 = *(const uint4*)&H16[(long long)(int)(cv3 & 0x1FFFF) * (DIM / 2) + il * 4];
        float v0 = __int_as_float((int)(cv0 >> 32));
        float v1 = __int_as_float((int)(cv1 >> 32));
        float v2 = __int_as_float((int)(cv2 >> 32));
        float v3 = __int_as_float((int)(cv3 >> 32));
#define ACC8(h, v)                                                        \
        acc[0] += (v) * bf2f((h).x & 0xFFFFu); acc[1] += (v) * bf2f((h).x >> 16); \
        acc[2] += (v) * bf2f((h).y & 0xFFFFu); acc[3] += (v) * bf2f((h).y >> 16); \
        acc[4] += (v) * bf2f((h).z & 0xFFFFu); acc[5] += (v) * bf2f((h).z >> 16); \
        acc[6] += (v) * bf2f((h).w & 0xFFFFu); acc[7] += (v) * bf2f((h).w >> 16);
        ACC8(h0, v0) ACC8(h1, v1) ACC8(h2, v2) ACC8(h3, v3)
    }
    for (; p < e; ++p) {
        long long cv = __builtin_nontemporal_load(&csr[p]);
        float v = __int_as_float((int)(cv >> 32));
        uint4 h = *(const uint4*)&H16[(long long)(int)(cv & 0x1FFFF) * (DIM / 2) + il * 4];
        ACC8(h, v)
    }
#undef ACC8

    float* op = &out[(long long)wid * DIM + il * 8];
    f32x4 o0 = {acc[0], acc[1], acc[2], acc[3]};
    f32x4 o1 = {acc[4], acc[5], acc[6], acc[7]};
    __builtin_nontemporal_store(o0, (f32x4*)op);
    __builtin_nontemporal_store(o1, (f32x4*)(op + 4));
}

extern "C" void kernel_launch(void* const* d_in, const int* in_sizes, int n_in,
                              void* d_out, int out_size, void* d_ws, size_t ws_size,
                              hipStream_t stream) {
    const float* x    = (const float*)d_in[0];
    const float* oh   = (const float*)d_in[1];
    const float* W0   = (const float*)d_in[2];
    const float* W1   = (const float*)d_in[3];
    const float* W2   = (const float*)d_in[4];
    const int*   rows = (const int*)d_in[5];
    const int*   cols = (const int*)d_in[6];
    const float* vals = (const float*)d_in[7];
    float* out = (float*)d_out;

    // workspace layout
    char* p = (char*)d_ws;
    size_t oW    = 0;                                   // WsumT bf16: 32 KB (64 KB reserved)
    size_t oH    = oW + 64 * 1024;                      // H bf16: 25.6 MB
    size_t oOff  = oH + (size_t)N_NODES * DIM * 2;      // off: N_NODES+1 (+pad)
    size_t oPs   = oOff + (size_t)(N_NODES + 32) * 4;   // psize: 256 ints
    size_t oPb   = oPs + 2048;                          // pbase: 257 ints
    size_t oSlab = oPb + 2048;                          // slabs: 256*8192*8B = 16.8 MB
    size_t oCsr  = oSlab + (size_t)NBIN * PCAP * 8;     // csr: 12.8 MB

    ushort_t*  WT    = (ushort_t*)(p + oW);
    uint_t*    H16   = (uint_t*)(p + oH);
    int*       off   = (int*)(p + oOff);
    int*       psize = (int*)(p + oPs);
    int*       pbase = (int*)(p + oPb);
    long long* slab  = (long long*)(p + oSlab);
    long long* csr   = (long long*)(p + oCsr);

    (void)hipMemsetAsync(psize, 0, NBIN * sizeof(int), stream);
    pass1_bin<<<P1_BLOCKS + 64, 256, 0, stream>>>(rows, cols, vals, psize, slab,
                                                  W0, W1, W2, WT);
    pscan<<<1, 64, 0, stream>>>(psize, pbase, off);
    gemm_mfma<<<(N_NODES + 63) / 64, 256, 0, stream>>>(x, oh, WT, H16);
    pass2_sort<<<NBIN, 256, 0, stream>>>(slab, psize, pbase, off, csr);
    gather_kernel<<<N_NODES / 16, 256, 0, stream>>>(H16, off, csr, out);
}